// Round 9
// baseline (279.156 us; speedup 1.0000x reference)
//
#include <hip/hip_runtime.h>
#include <hip/hip_bf16.h>

#define BB 256
#define PP 48
#define NN 64
#define EPSBN 1e-5f

typedef __attribute__((ext_vector_type(8))) short bf16x8;
typedef __attribute__((ext_vector_type(4))) float f32x4;

// ---- LDS regions (ushort offsets), total 81920 ushorts = 163840 B (160 KiB) ----
// 8-wave (512-thread) fold-p layout:
#define BIGO 0       // 32768: fr1R/[+16384]fr1S -> fr2 [128][256]   | N: fo1 [256][128] -> fo2 [128][256]
#define S1SO 32768   // 16384: S1S [64][256]                          | N: act1N [64][256]
#define S1RO 49152   // 16384: S1R [64][256]; cols 0..63 ebar; N: +xn cols 64..127 -> fo3 [64][128]
#define F3LO 65536   //  8192: fr3 [64][128] (phase E B-operand)      | N: act2N [64][128]
#define A2WO 73728   //  5120: phase E: 8 waves x 640 ([16][40] stride-40)
#define XNTP 73728   //  4096: prologue xnT [64][64] (aliases A2WO; dead before phase E)
#define B2LO 81408   //   256: fr2_b as 128 floats (phase E only)
#define REDO 81664   //   256: phase-N-end red/h1/h2 floats
#define LDSE 81920

union U8 { bf16x8 v; unsigned u[4]; };

__device__ __forceinline__ unsigned pku(float a, float b) {
    union { __hip_bfloat162 h; unsigned u; } cv;
    cv.h = __float22bfloat162_rn(make_float2(a, b));
    return cv.u;
}
__device__ __forceinline__ ushort f2b(float f) {
    union { float f; unsigned u; } a; a.f = f;
    unsigned u = a.u + 0x7FFFu + ((a.u >> 16) & 1u);
    return (ushort)(u >> 16);
}
__device__ __forceinline__ float loF(unsigned u) { union { unsigned x; float f; } c; c.x = u << 16; return c.f; }
__device__ __forceinline__ float hiF(unsigned u) { union { unsigned x; float f; } c; c.x = u & 0xffff0000u; return c.f; }

__device__ __forceinline__ int sidx(int row, int k, int kpad) {
    return row * kpad + ((((k >> 3) ^ (row & 7)) << 3) | (k & 7));
}
__device__ __forceinline__ bf16x8 ldfrag(const ushort* buf, int row, int k, int kpad) {
    return *(const bf16x8*)(buf + row * kpad + (((k >> 3) ^ (row & 7)) << 3));
}
// [16][40] wave-private buffer: 80 B row stride spreads rows over banks (~2-way)
__device__ __forceinline__ bf16x8 ldfrag40(const ushort* buf, int row, int k) {
    return *(const bf16x8*)(buf + row * 40 + k);
}
__device__ __forceinline__ f32x4 MFMA(bf16x8 a, bf16x8 b, f32x4 c) {
    return __builtin_amdgcn_mfma_f32_16x16x32_bf16(a, b, c, 0, 0, 0);
}
__device__ __forceinline__ void stAct(ushort* buf, int row, int c0, int kpad, f32x4 a, float4 bi) {
    uint2 o;
    o.x = pku(fmaxf(a[0] + bi.x, 0.f), fmaxf(a[1] + bi.y, 0.f));
    o.y = pku(fmaxf(a[2] + bi.z, 0.f), fmaxf(a[3] + bi.w, 0.f));
    *(uint2*)(buf + row * kpad + ((((c0 >> 3) ^ (row & 7)) << 3) | (c0 & 7))) = o;
}
// bias folded into accumulator init: store relu(acc); stride-40 variant
__device__ __forceinline__ void stAct040(ushort* buf, int row, int c0, f32x4 a) {
    uint2 o;
    o.x = pku(fmaxf(a[0], 0.f), fmaxf(a[1], 0.f));
    o.y = pku(fmaxf(a[2], 0.f), fmaxf(a[3], 0.f));
    *(uint2*)(buf + row * 40 + c0) = o;
}
__device__ __forceinline__ void stRaw(ushort* buf, int row, int c0, int kpad, f32x4 a, float4 bi) {
    uint2 o;
    o.x = pku(a[0] + bi.x, a[1] + bi.y);
    o.y = pku(a[2] + bi.z, a[3] + bi.w);
    *(uint2*)(buf + row * kpad + ((((c0 >> 3) ^ (row & 7)) << 3) | (c0 & 7))) = o;
}

// ---------------- batchnorm stats ----------------
__global__ __launch_bounds__(256) void bn_stats_kernel(
    const float* __restrict__ x, const float* __restrict__ gamma,
    const float* __restrict__ beta, float* __restrict__ scale, float* __restrict__ bias)
{
    __shared__ float s_sum[256], s_sq[256];
    int p = blockIdx.x, t = threadIdx.x;
    float sum = 0.f, sq = 0.f;
    for (int i = t; i < BB * NN; i += 256) {
        int b = i >> 6, n = i & 63;
        float v = x[b * PP * NN + p * NN + n];
        sum += v; sq += v * v;
    }
    s_sum[t] = sum; s_sq[t] = sq;
    __syncthreads();
    for (int off = 128; off > 0; off >>= 1) {
        if (t < off) { s_sum[t] += s_sum[t + off]; s_sq[t] += s_sq[t + off]; }
        __syncthreads();
    }
    if (t == 0) {
        float inv = 1.f / (float)(BB * NN);
        float mean = s_sum[0] * inv;
        float var  = s_sq[0] * inv - mean * mean;
        float sc   = gamma[p] * rsqrtf(var + EPSBN);
        scale[p] = sc;
        bias[p]  = beta[p] - mean * sc;
    }
}

// ---------------- mega kernel: one block per batch, 8 waves (fold-p) ----------------
// R8: fold the p-loop — each wave processes ALL 64 edge-columns of its
// receiver per ks pass (acc2[8][4] = 128 AGPR). One fr2 Af read now feeds
// 4 MFMAs (was 2), cutting phase-E LDS ops/receiver ~26%; 64/8 receivers
// balance perfectly (12-wave split wasted 12% on the 6-vs-5.33 tail).
// Fits: 128 AGPR + ~76 arch ~= 204 < 256 at 2 waves/SIMD (fr3 is in LDS).
__global__ __launch_bounds__(512, 2) void meg_kernel(
    const float* __restrict__ x,
    const float* __restrict__ scl, const float* __restrict__ bia,
    const float* __restrict__ fr1_w, const float* __restrict__ fr1_b,
    const float* __restrict__ fr2_w, const float* __restrict__ fr2_b,
    const float* __restrict__ fr3_w, const float* __restrict__ fr3_b,
    const float* __restrict__ fo1_w, const float* __restrict__ fo1_b,
    const float* __restrict__ fo2_w, const float* __restrict__ fo2_b,
    const float* __restrict__ fo3_w, const float* __restrict__ fo3_b,
    const float* __restrict__ fc1_w, const float* __restrict__ fc1_b,
    const float* __restrict__ fc2_w, const float* __restrict__ fc2_b,
    const float* __restrict__ fc3_w, const float* __restrict__ fc3_b,
    float* __restrict__ out)
{
    __shared__ __align__(16) ushort L[LDSE];

    int b = blockIdx.x, t = threadIdx.x;
    int w = t >> 6, l = t & 63, lx = l & 15, lq = l >> 4;

    // ---- xnT [64][64] (cols 48..63 zero) @ XNTP (prologue only)
    for (int i = t; i < 4096; i += 512) {
        int n = i >> 6, k = i & 63;
        float v = (k < PP) ? x[b * PP * NN + k * NN + n] * scl[k] + bia[k] : 0.f;
        L[XNTP + sidx(n, k, 64)] = f2b(v);
    }
    // ---- fr1 receiver / sender halves into BIG
    for (int i = t; i < 16384; i += 512) {
        int ch = i >> 6, k = i & 63;
        L[BIGO + sidx(ch, k, 64)]         = f2b((k < PP) ? fr1_w[ch * 96 + k] : 0.f);
        L[BIGO + 16384 + sidx(ch, k, 64)] = f2b((k < PP) ? fr1_w[ch * 96 + PP + k] : 0.f);
    }
    // ---- fr3 [64][128] -> F3LO
    for (int i = t; i < 4096; i += 512) {
        int ch = i >> 6, k2 = (i & 63) * 2;
        float2 v = *(const float2*)(fr3_w + ch * 128 + k2);
        *(unsigned*)(L + F3LO + sidx(ch, k2, 128)) = pku(v.x, v.y);
    }
    // ---- fr2 bias table -> B2LO (128 floats)
    if (t < 128) ((float*)(L + B2LO))[t] = fr2_b[t];
    __syncthreads();

    // ---- GEMM1+2 fused: S1R = fr1R.xn + b1, S1S = fr1S.xn (16 m-tiles over 8 waves)
    for (int mt = w; mt < 16; mt += 8) {
        f32x4 aR[4], aS[4];
#pragma unroll
        for (int nt = 0; nt < 4; ++nt) { aR[nt] = (f32x4){0.f,0.f,0.f,0.f}; aS[nt] = (f32x4){0.f,0.f,0.f,0.f}; }
#pragma unroll
        for (int ks = 0; ks < 2; ++ks) {
            bf16x8 AfR = ldfrag(L + BIGO,         mt * 16 + lx, ks * 32 + lq * 8, 64);
            bf16x8 AfS = ldfrag(L + BIGO + 16384, mt * 16 + lx, ks * 32 + lq * 8, 64);
#pragma unroll
            for (int nt = 0; nt < 4; ++nt) {
                bf16x8 Bf = ldfrag(L + XNTP, nt * 16 + lx, ks * 32 + lq * 8, 64);
                aR[nt] = MFMA(AfR, Bf, aR[nt]);
                aS[nt] = MFMA(AfS, Bf, aS[nt]);
            }
        }
        int ch0 = mt * 16 + lq * 4;
        float4 bi = *(const float4*)(fr1_b + ch0);
        float4 zb = make_float4(0.f, 0.f, 0.f, 0.f);
#pragma unroll
        for (int nt = 0; nt < 4; ++nt) {
            stRaw(L + S1RO, nt * 16 + lx, ch0, 256, aR[nt], bi);
            stRaw(L + S1SO, nt * 16 + lx, ch0, 256, aS[nt], zb);
        }
    }
    __syncthreads();   // BIG/XNTP reads done; restage fr2 below

    // ---- fr2 [128][256] -> BIG
    for (int i = t; i < 16384; i += 512) {
        int ch = i >> 7, k2 = (i & 127) * 2;
        float2 v = *(const float2*)(fr2_w + ch * 256 + k2);
        *(unsigned*)(L + BIGO + sidx(ch, k2, 256)) = pku(v.x, v.y);
    }
    float b3c[4];
#pragma unroll
    for (int n3 = 0; n3 < 4; ++n3) b3c[n3] = fr3_b[n3 * 16 + lx];
    __syncthreads();

    // ================= phase E: 8 receivers per wave, all 64 edge-cols per pass =================
    ushort* a2w = L + A2WO + w * 640;     // wave-private [16][40]
    const float* b2L = (const float*)(L + B2LO);
#pragma unroll 1
    for (int r = w; r < 64; r += 8) {
        // sender indices for the 4 col-blocks (edge e = cc*16+lx; sender = e + (e>=r); slot 63 padded)
        int e0 = lx,      s0 = e0 + (e0 >= r);
        int e1 = 16 + lx, s1 = e1 + (e1 >= r);
        int e2 = 32 + lx, s2 = e2 + (e2 >= r);
        int e3 = 48 + lx, s3 = e3 + (e3 >= r); if (s3 > 63) s3 = 63;

        f32x4 acc2[8][4];
#pragma unroll
        for (int m = 0; m < 8; ++m) {
            float4 bv = *(const float4*)(b2L + m * 16 + lq * 4);   // broadcast read
            f32x4 bi; bi[0] = bv.x; bi[1] = bv.y; bi[2] = bv.z; bi[3] = bv.w;
            acc2[m][0] = bi; acc2[m][1] = bi; acc2[m][2] = bi; acc2[m][3] = bi;
        }
#pragma unroll
        for (int ks = 0; ks < 8; ++ks) {
            int ko = ks * 32 + lq * 8;
            U8 fr, f0, f1, f2, f3;
            fr.v = ldfrag(L + S1RO, r,  ko, 256);   // wave-uniform row: broadcast
            f0.v = ldfrag(L + S1SO, s0, ko, 256);
            f1.v = ldfrag(L + S1SO, s1, ko, 256);
            f2.v = ldfrag(L + S1SO, s2, ko, 256);
            f3.v = ldfrag(L + S1SO, s3, ko, 256);
            U8 b0, b1, b2, b3;
#pragma unroll
            for (int jj = 0; jj < 4; ++jj) {
                float r0 = loF(fr.u[jj]), r1 = hiF(fr.u[jj]);
                b0.u[jj] = pku(fmaxf(r0 + loF(f0.u[jj]), 0.f), fmaxf(r1 + hiF(f0.u[jj]), 0.f));
                b1.u[jj] = pku(fmaxf(r0 + loF(f1.u[jj]), 0.f), fmaxf(r1 + hiF(f1.u[jj]), 0.f));
                b2.u[jj] = pku(fmaxf(r0 + loF(f2.u[jj]), 0.f), fmaxf(r1 + hiF(f2.u[jj]), 0.f));
                b3.u[jj] = pku(fmaxf(r0 + loF(f3.u[jj]), 0.f), fmaxf(r1 + hiF(f3.u[jj]), 0.f));
            }
#pragma unroll
            for (int m = 0; m < 8; ++m) {
                bf16x8 Af = ldfrag(L + BIGO, m * 16 + lx, ko, 256);   // feeds 4 MFMAs
                acc2[m][0] = MFMA(Af, b0.v, acc2[m][0]);
                acc2[m][1] = MFMA(Af, b1.v, acc2[m][1]);
                acc2[m][2] = MFMA(Af, b2.v, acc2[m][2]);
                acc2[m][3] = MFMA(Af, b3.v, acc2[m][3]);
            }
        }
        // ---- epilogue: fr3 GEMM per col-block through [16][40] quarters
        float part[4] = {0.f, 0.f, 0.f, 0.f};
#pragma unroll
        for (int cc = 0; cc < 4; ++cc) {
            f32x4 acc3[4];
#pragma unroll
            for (int n3 = 0; n3 < 4; ++n3) acc3[n3] = (f32x4){0.f,0.f,0.f,0.f};
#pragma unroll
            for (int h = 0; h < 4; ++h) {
                stAct040(a2w, lx, lq * 4,      acc2[2 * h][cc]);
                stAct040(a2w, lx, 16 + lq * 4, acc2[2 * h + 1][cc]);
                bf16x8 af = ldfrag40(a2w, lx, lq * 8);
#pragma unroll
                for (int n3 = 0; n3 < 4; ++n3) {
                    bf16x8 bW = ldfrag(L + F3LO, n3 * 16 + lx, h * 32 + lq * 8, 128);
                    acc3[n3] = MFMA(af, bW, acc3[n3]);
                }
            }
            bool mpad = (cc == 3) && (lq == 3);   // padded edge slot 63 = (cc3, lq3, j3)
#pragma unroll
            for (int n3 = 0; n3 < 4; ++n3) {
                float bv = b3c[n3];
                float s = fmaxf(acc3[n3][0] + bv, 0.f) + fmaxf(acc3[n3][1] + bv, 0.f)
                        + fmaxf(acc3[n3][2] + bv, 0.f);
                float s3v = fmaxf(acc3[n3][3] + bv, 0.f);
                part[n3] += s + (mpad ? 0.f : s3v);
            }
        }
#pragma unroll
        for (int n3 = 0; n3 < 4; ++n3) {
            part[n3] += __shfl_xor(part[n3], 16, 64);
            part[n3] += __shfl_xor(part[n3], 32, 64);
        }
        if (lq == 0) {
#pragma unroll
            for (int n3 = 0; n3 < 4; ++n3)
                L[S1RO + sidx(r, n3 * 16 + lx, 256)] = f2b(part[n3]);
        }
    }
    __syncthreads();

    // ================= phase N =================
    // fo1 -> BIG [256][128] (cols 0..63 ebar part, 64..111 xn part)
    for (int i = t; i < 32768; i += 512) {
        int ch = i >> 7, k = i & 127;
        float v = 0.f;
        if (k < 64)       v = fo1_w[ch * 112 + PP + k];
        else if (k < 112) v = fo1_w[ch * 112 + (k - 64)];
        L[BIGO + sidx(ch, k, 128)] = f2b(v);
    }
    // xn -> S1RO cols 64..127 (48 real + 16 zero); ebar already in cols 0..63
    for (int i = t; i < 4096; i += 512) {
        int n = i >> 6, k = i & 63;
        float v = (k < PP) ? x[b * PP * NN + k * NN + n] * scl[k] + bia[k] : 0.f;
        L[S1RO + sidx(n, 64 + k, 256)] = f2b(v);
    }
    __syncthreads();

    // L1N: M=256 (16 m-tiles over 8 waves), N=64 nodes, K=128 (all from S1RO)
    for (int mt = w; mt < 16; mt += 8) {
        f32x4 accN[4];
#pragma unroll
        for (int nt = 0; nt < 4; ++nt) accN[nt] = (f32x4){0.f,0.f,0.f,0.f};
#pragma unroll
        for (int ks = 0; ks < 4; ++ks) {
            bf16x8 Af = ldfrag(L + BIGO, mt * 16 + lx, ks * 32 + lq * 8, 128);
#pragma unroll
            for (int nt = 0; nt < 4; ++nt) {
                bf16x8 Bf = ldfrag(L + S1RO, nt * 16 + lx, ks * 32 + lq * 8, 256);
                accN[nt] = MFMA(Af, Bf, accN[nt]);
            }
        }
        int ch0 = mt * 16 + lq * 4;
        float4 bi = *(const float4*)(fo1_b + ch0);
#pragma unroll
        for (int nt = 0; nt < 4; ++nt)
            stAct(L + S1SO, nt * 16 + lx, ch0, 256, accN[nt], bi);
    }
    __syncthreads();   // BIG/S1RO reads done

    // fo2 -> BIG [128][256]; fo3 -> S1RO [64][128]
    for (int i = t; i < 16384; i += 512) {
        int ch = i >> 7, k2 = (i & 127) * 2;
        float2 v = *(const float2*)(fo2_w + ch * 256 + k2);
        *(unsigned*)(L + BIGO + sidx(ch, k2, 256)) = pku(v.x, v.y);
    }
    for (int i = t; i < 4096; i += 512) {
        int ch = i >> 6, k2 = (i & 63) * 2;
        float2 v = *(const float2*)(fo3_w + ch * 128 + k2);
        *(unsigned*)(L + S1RO + sidx(ch, k2, 128)) = pku(v.x, v.y);
    }
    __syncthreads();

    // L2N: M=128 (8 waves), N=64, K=256 -> act2N @ F3LO [64][128]
    {
        f32x4 a2N[4];
#pragma unroll
        for (int nt = 0; nt < 4; ++nt) a2N[nt] = (f32x4){0.f,0.f,0.f,0.f};
#pragma unroll
        for (int ks = 0; ks < 8; ++ks) {
            bf16x8 Af = ldfrag(L + BIGO, w * 16 + lx, ks * 32 + lq * 8, 256);
#pragma unroll
            for (int nt = 0; nt < 4; ++nt) {
                bf16x8 Bf = ldfrag(L + S1SO, nt * 16 + lx, ks * 32 + lq * 8, 256);
                a2N[nt] = MFMA(Af, Bf, a2N[nt]);
            }
        }
        int ch0 = w * 16 + lq * 4;
        float4 bi = *(const float4*)(fo2_b + ch0);
#pragma unroll
        for (int nt = 0; nt < 4; ++nt)
            stAct(L + F3LO, nt * 16 + lx, ch0, 128, a2N[nt], bi);
    }
    __syncthreads();

    // L3N: M=64 (fo3 ch), N=64 nodes, K=128 (waves 0..3); relu+bias, sum over nodes
    if (w < 4) {
        f32x4 a3N[4];
#pragma unroll
        for (int nt = 0; nt < 4; ++nt) a3N[nt] = (f32x4){0.f,0.f,0.f,0.f};
#pragma unroll
        for (int ks3 = 0; ks3 < 4; ++ks3) {
            bf16x8 Af = ldfrag(L + S1RO, 16 * w + lx, ks3 * 32 + lq * 8, 128);
#pragma unroll
            for (int nt = 0; nt < 4; ++nt) {
                bf16x8 Bf = ldfrag(L + F3LO, nt * 16 + lx, ks3 * 32 + lq * 8, 128);
                a3N[nt] = MFMA(Af, Bf, a3N[nt]);
            }
        }
        float4 b3 = *(const float4*)(fo3_b + 16 * w + lq * 4);
        float o0 = 0.f, o1 = 0.f, o2 = 0.f, o3 = 0.f;
#pragma unroll
        for (int nt = 0; nt < 4; ++nt) {
            o0 += fmaxf(a3N[nt][0] + b3.x, 0.f);
            o1 += fmaxf(a3N[nt][1] + b3.y, 0.f);
            o2 += fmaxf(a3N[nt][2] + b3.z, 0.f);
            o3 += fmaxf(a3N[nt][3] + b3.w, 0.f);
        }
#pragma unroll
        for (int off = 8; off >= 1; off >>= 1) {
            o0 += __shfl_xor(o0, off, 16);
            o1 += __shfl_xor(o1, off, 16);
            o2 += __shfl_xor(o2, off, 16);
            o3 += __shfl_xor(o3, off, 16);
        }
        if (lx == 0) {
            float* red = (float*)(L + REDO);
            *(float4*)&red[16 * w + lq * 4] = make_float4(o0, o1, o2, o3);
        }
    }
    __syncthreads();

    // ---- final FCs (fp32)
    {
        float* red = (float*)(L + REDO);
        float* h1  = red + 64;
        float* h2  = red + 96;
        if (t < 25) {
            float s = fc1_b[t];
            for (int k = 0; k < 64; ++k) s += fc1_w[t * 64 + k] * red[k];
            h1[t] = s;
        }
        __syncthreads();
        if (t < 15) {
            float s = fc2_b[t];
            for (int k = 0; k < 25; ++k) s += fc2_w[t * 25 + k] * h1[k];
            h2[t] = s;
        }
        __syncthreads();
        if (t < 5) {
            float s = fc3_b[t];
            for (int k = 0; k < 15; ++k) s += fc3_w[t * 15 + k] * h2[k];
            out[b * 5 + t] = s;
        }
    }
}

extern "C" void kernel_launch(void* const* d_in, const int* in_sizes, int n_in,
                              void* d_out, int out_size, void* d_ws, size_t ws_size,
                              hipStream_t stream)
{
    const float* x        = (const float*)d_in[0];
    const float* bn_gamma = (const float*)d_in[3];
    const float* bn_beta  = (const float*)d_in[4];
    const float* fr1_w = (const float*)d_in[5];
    const float* fr1_b = (const float*)d_in[6];
    const float* fr2_w = (const float*)d_in[7];
    const float* fr2_b = (const float*)d_in[8];
    const float* fr3_w = (const float*)d_in[9];
    const float* fr3_b = (const float*)d_in[10];
    const float* fo1_w = (const float*)d_in[11];
    const float* fo1_b = (const float*)d_in[12];
    const float* fo2_w = (const float*)d_in[13];
    const float* fo2_b = (const float*)d_in[14];
    const float* fo3_w = (const float*)d_in[15];
    const float* fo3_b = (const float*)d_in[16];
    const float* fc1_w = (const float*)d_in[17];
    const float* fc1_b = (const float*)d_in[18];
    const float* fc2_w = (const float*)d_in[19];
    const float* fc2_b = (const float*)d_in[20];
    const float* fc3_w = (const float*)d_in[21];
    const float* fc3_b = (const float*)d_in[22];

    float* ws    = (float*)d_ws;
    float* scale = ws;
    float* bias  = ws + 64;
    float* out   = (float*)d_out;

    bn_stats_kernel<<<dim3(PP), dim3(256), 0, stream>>>(x, bn_gamma, bn_beta, scale, bias);
    meg_kernel<<<dim3(BB), dim3(512), 0, stream>>>(
        x, scale, bias,
        fr1_w, fr1_b, fr2_w, fr2_b, fr3_w, fr3_b,
        fo1_w, fo1_b, fo2_w, fo2_b, fo3_w, fo3_b,
        fc1_w, fc1_b, fc2_w, fc2_b, fc3_w, fc3_b, out);
}

// Round 10
// 256.486 us; speedup vs baseline: 1.0884x; 1.0884x over previous
//
#include <hip/hip_runtime.h>
#include <hip/hip_bf16.h>

#define BB 256
#define PP 48
#define NN 64
#define EPSBN 1e-5f

typedef __attribute__((ext_vector_type(8))) short bf16x8;
typedef __attribute__((ext_vector_type(4))) float f32x4;

// ---- LDS regions (ushort offsets), total 81920 ushorts = 163840 B (160 KiB) ----
// 12-wave (768-thread) layout:
#define BIGO 0       // 32768: fr1R/[+16384]fr1S -> fr2 [128][256]   | N: fo1 [256][128] -> fo2 [128][256]
#define S1SO 32768   // 16384: S1S [64][256]                          | N: act1N [64][256]
#define S1RO 49152   // 16384: S1R [64][256]; cols 0..63 ebar; N: +xn cols 64..127 -> fo3 [64][128]
#define F3LO 65536   //  8192: fr3 [64][128] (phase E B-operand)      | N: act2N [64][128]
#define A2WO 73728   //  7680: phase E: 12 waves x 640 ([16][40] stride-40)
#define XNTP 73728   //  4096: prologue xnT [64][64] (aliases A2WO; dead before phase E)
#define B2LO 81408   //   256: fr2_b as 128 floats (phase E only)
#define REDO 81664   //   256: phase-N-end red/h1/h2 floats
#define LDSE 81920

union U8 { bf16x8 v; unsigned u[4]; };

__device__ __forceinline__ unsigned pku(float a, float b) {
    union { __hip_bfloat162 h; unsigned u; } cv;
    cv.h = __float22bfloat162_rn(make_float2(a, b));
    return cv.u;
}
__device__ __forceinline__ ushort f2b(float f) {
    union { float f; unsigned u; } a; a.f = f;
    unsigned u = a.u + 0x7FFFu + ((a.u >> 16) & 1u);
    return (ushort)(u >> 16);
}
__device__ __forceinline__ float loF(unsigned u) { union { unsigned x; float f; } c; c.x = u << 16; return c.f; }
__device__ __forceinline__ float hiF(unsigned u) { union { unsigned x; float f; } c; c.x = u & 0xffff0000u; return c.f; }

__device__ __forceinline__ int sidx(int row, int k, int kpad) {
    return row * kpad + ((((k >> 3) ^ (row & 7)) << 3) | (k & 7));
}
__device__ __forceinline__ bf16x8 ldfrag(const ushort* buf, int row, int k, int kpad) {
    return *(const bf16x8*)(buf + row * kpad + (((k >> 3) ^ (row & 7)) << 3));
}
// [16][40] wave-private buffer: 80 B row stride spreads rows over banks (~2-way)
__device__ __forceinline__ bf16x8 ldfrag40(const ushort* buf, int row, int k) {
    return *(const bf16x8*)(buf + row * 40 + k);
}
__device__ __forceinline__ f32x4 MFMA(bf16x8 a, bf16x8 b, f32x4 c) {
    return __builtin_amdgcn_mfma_f32_16x16x32_bf16(a, b, c, 0, 0, 0);
}
__device__ __forceinline__ void stAct(ushort* buf, int row, int c0, int kpad, f32x4 a, float4 bi) {
    uint2 o;
    o.x = pku(fmaxf(a[0] + bi.x, 0.f), fmaxf(a[1] + bi.y, 0.f));
    o.y = pku(fmaxf(a[2] + bi.z, 0.f), fmaxf(a[3] + bi.w, 0.f));
    *(uint2*)(buf + row * kpad + ((((c0 >> 3) ^ (row & 7)) << 3) | (c0 & 7))) = o;
}
// bias folded into accumulator init: store relu(acc); stride-40 variant
__device__ __forceinline__ void stAct040(ushort* buf, int row, int c0, f32x4 a) {
    uint2 o;
    o.x = pku(fmaxf(a[0], 0.f), fmaxf(a[1], 0.f));
    o.y = pku(fmaxf(a[2], 0.f), fmaxf(a[3], 0.f));
    *(uint2*)(buf + row * 40 + c0) = o;
}
__device__ __forceinline__ void stRaw(ushort* buf, int row, int c0, int kpad, f32x4 a, float4 bi) {
    uint2 o;
    o.x = pku(a[0] + bi.x, a[1] + bi.y);
    o.y = pku(a[2] + bi.z, a[3] + bi.w);
    *(uint2*)(buf + row * kpad + ((((c0 >> 3) ^ (row & 7)) << 3) | (c0 & 7))) = o;
}

// ---------------- batchnorm stats ----------------
__global__ __launch_bounds__(256) void bn_stats_kernel(
    const float* __restrict__ x, const float* __restrict__ gamma,
    const float* __restrict__ beta, float* __restrict__ scale, float* __restrict__ bias)
{
    __shared__ float s_sum[256], s_sq[256];
    int p = blockIdx.x, t = threadIdx.x;
    float sum = 0.f, sq = 0.f;
    for (int i = t; i < BB * NN; i += 256) {
        int b = i >> 6, n = i & 63;
        float v = x[b * PP * NN + p * NN + n];
        sum += v; sq += v * v;
    }
    s_sum[t] = sum; s_sq[t] = sq;
    __syncthreads();
    for (int off = 128; off > 0; off >>= 1) {
        if (t < off) { s_sum[t] += s_sum[t + off]; s_sq[t] += s_sq[t + off]; }
        __syncthreads();
    }
    if (t == 0) {
        float inv = 1.f / (float)(BB * NN);
        float mean = s_sum[0] * inv;
        float var  = s_sq[0] * inv - mean * mean;
        float sc   = gamma[p] * rsqrtf(var + EPSBN);
        scale[p] = sc;
        bias[p]  = beta[p] - mean * sc;
    }
}

// ---------------- mega kernel: one block per batch, 12 waves (3/SIMD) ----------------
// R9 = R7 (best: 165 us; 12 waves beat 8-wave fold-p despite more LDS traffic)
// + epilogue restructure: h-outer/cc-inner so each fr3 bW[4] load serves both
// cc halves (32 -> 16 bW reads per (r,p); epilogue is on the serial
// acc2->acc3 drain path). acc3 becomes [2][4]; epilogue arch pressure stays
// under the kernel's ks-loop peak, so no new spills expected.
__global__ __launch_bounds__(768, 3) void meg_kernel(
    const float* __restrict__ x,
    const float* __restrict__ scl, const float* __restrict__ bia,
    const float* __restrict__ fr1_w, const float* __restrict__ fr1_b,
    const float* __restrict__ fr2_w, const float* __restrict__ fr2_b,
    const float* __restrict__ fr3_w, const float* __restrict__ fr3_b,
    const float* __restrict__ fo1_w, const float* __restrict__ fo1_b,
    const float* __restrict__ fo2_w, const float* __restrict__ fo2_b,
    const float* __restrict__ fo3_w, const float* __restrict__ fo3_b,
    const float* __restrict__ fc1_w, const float* __restrict__ fc1_b,
    const float* __restrict__ fc2_w, const float* __restrict__ fc2_b,
    const float* __restrict__ fc3_w, const float* __restrict__ fc3_b,
    float* __restrict__ out)
{
    __shared__ __align__(16) ushort L[LDSE];

    int b = blockIdx.x, t = threadIdx.x;
    int w = t >> 6, l = t & 63, lx = l & 15, lq = l >> 4;

    // ---- xnT [64][64] (cols 48..63 zero) @ XNTP (prologue only)
    for (int i = t; i < 4096; i += 768) {
        int n = i >> 6, k = i & 63;
        float v = (k < PP) ? x[b * PP * NN + k * NN + n] * scl[k] + bia[k] : 0.f;
        L[XNTP + sidx(n, k, 64)] = f2b(v);
    }
    // ---- fr1 receiver / sender halves into BIG
    for (int i = t; i < 16384; i += 768) {
        int ch = i >> 6, k = i & 63;
        L[BIGO + sidx(ch, k, 64)]         = f2b((k < PP) ? fr1_w[ch * 96 + k] : 0.f);
        L[BIGO + 16384 + sidx(ch, k, 64)] = f2b((k < PP) ? fr1_w[ch * 96 + PP + k] : 0.f);
    }
    // ---- fr3 [64][128] -> F3LO
    for (int i = t; i < 4096; i += 768) {
        int ch = i >> 6, k2 = (i & 63) * 2;
        float2 v = *(const float2*)(fr3_w + ch * 128 + k2);
        *(unsigned*)(L + F3LO + sidx(ch, k2, 128)) = pku(v.x, v.y);
    }
    // ---- fr2 bias table -> B2LO (128 floats)
    if (t < 128) ((float*)(L + B2LO))[t] = fr2_b[t];
    __syncthreads();

    // ---- GEMM1+2 fused: S1R = fr1R.xn + b1, S1S = fr1S.xn (16 m-tiles over 12 waves)
    for (int mt = w; mt < 16; mt += 12) {
        f32x4 aR[4], aS[4];
#pragma unroll
        for (int nt = 0; nt < 4; ++nt) { aR[nt] = (f32x4){0.f,0.f,0.f,0.f}; aS[nt] = (f32x4){0.f,0.f,0.f,0.f}; }
#pragma unroll
        for (int ks = 0; ks < 2; ++ks) {
            bf16x8 AfR = ldfrag(L + BIGO,         mt * 16 + lx, ks * 32 + lq * 8, 64);
            bf16x8 AfS = ldfrag(L + BIGO + 16384, mt * 16 + lx, ks * 32 + lq * 8, 64);
#pragma unroll
            for (int nt = 0; nt < 4; ++nt) {
                bf16x8 Bf = ldfrag(L + XNTP, nt * 16 + lx, ks * 32 + lq * 8, 64);
                aR[nt] = MFMA(AfR, Bf, aR[nt]);
                aS[nt] = MFMA(AfS, Bf, aS[nt]);
            }
        }
        int ch0 = mt * 16 + lq * 4;
        float4 bi = *(const float4*)(fr1_b + ch0);
        float4 zb = make_float4(0.f, 0.f, 0.f, 0.f);
#pragma unroll
        for (int nt = 0; nt < 4; ++nt) {
            stRaw(L + S1RO, nt * 16 + lx, ch0, 256, aR[nt], bi);
            stRaw(L + S1SO, nt * 16 + lx, ch0, 256, aS[nt], zb);
        }
    }
    __syncthreads();   // BIG/XNTP reads done; restage fr2 below

    // ---- fr2 [128][256] -> BIG
    for (int i = t; i < 16384; i += 768) {
        int ch = i >> 7, k2 = (i & 127) * 2;
        float2 v = *(const float2*)(fr2_w + ch * 256 + k2);
        *(unsigned*)(L + BIGO + sidx(ch, k2, 256)) = pku(v.x, v.y);
    }
    float b3c[4];
#pragma unroll
    for (int n3 = 0; n3 < 4; ++n3) b3c[n3] = fr3_b[n3 * 16 + lx];
    __syncthreads();

    // ================= phase E: receivers strided over 12 waves, zero barriers =================
    ushort* a2w = L + A2WO + w * 640;     // wave-private [16][40]
    const float* b2L = (const float*)(L + B2LO);
#pragma unroll 1
    for (int r = w; r < 64; r += 12) {
        float part[4] = {0.f, 0.f, 0.f, 0.f};
#pragma unroll 1
        for (int p = 0; p < 2; ++p) {
            int eA = p * 32 + lx, eB = eA + 16;
            int sA = eA + (eA >= r);
            int sB = eB + (eB >= r); if (sB > 63) sB = 63;   // pad edge 63

            f32x4 acc2[8][2];
#pragma unroll
            for (int m = 0; m < 8; ++m) {
                // fr2 bias from LDS table: one broadcast read per m
                float4 bv = *(const float4*)(b2L + m * 16 + lq * 4);
                f32x4 bi; bi[0] = bv.x; bi[1] = bv.y; bi[2] = bv.z; bi[3] = bv.w;
                acc2[m][0] = bi; acc2[m][1] = bi;
            }
#pragma unroll
            for (int ks = 0; ks < 8; ++ks) {
                int ko = ks * 32 + lq * 8;
                U8 fr, fa, fb;
                fr.v = ldfrag(L + S1RO, r,  ko, 256);   // wave-uniform row: broadcast
                fa.v = ldfrag(L + S1SO, sA, ko, 256);
                fb.v = ldfrag(L + S1SO, sB, ko, 256);
                U8 bA, bB;
#pragma unroll
                for (int jj = 0; jj < 4; ++jj) {
                    float r0 = loF(fr.u[jj]), r1 = hiF(fr.u[jj]);
                    bA.u[jj] = pku(fmaxf(r0 + loF(fa.u[jj]), 0.f), fmaxf(r1 + hiF(fa.u[jj]), 0.f));
                    bB.u[jj] = pku(fmaxf(r0 + loF(fb.u[jj]), 0.f), fmaxf(r1 + hiF(fb.u[jj]), 0.f));
                }
#pragma unroll
                for (int m = 0; m < 8; ++m) {
                    bf16x8 Af = ldfrag(L + BIGO, m * 16 + lx, ko, 256);
                    acc2[m][0] = MFMA(Af, bA.v, acc2[m][0]);
                    acc2[m][1] = MFMA(Af, bB.v, acc2[m][1]);
                }
            }
            // ---- epilogue: fr3 GEMM through [16][40] quarters, h-outer so each
            // bW[4] load serves both cc halves (16 bW reads/(r,p), was 32)
            f32x4 acc3[2][4];
#pragma unroll
            for (int cc = 0; cc < 2; ++cc)
#pragma unroll
                for (int n3 = 0; n3 < 4; ++n3) acc3[cc][n3] = (f32x4){0.f,0.f,0.f,0.f};
#pragma unroll
            for (int h = 0; h < 4; ++h) {
                bf16x8 bW[4];
#pragma unroll
                for (int n3 = 0; n3 < 4; ++n3)
                    bW[n3] = ldfrag(L + F3LO, n3 * 16 + lx, h * 32 + lq * 8, 128);
#pragma unroll
                for (int cc = 0; cc < 2; ++cc) {
                    stAct040(a2w, lx, lq * 4,      acc2[2 * h][cc]);
                    stAct040(a2w, lx, 16 + lq * 4, acc2[2 * h + 1][cc]);
                    bf16x8 af = ldfrag40(a2w, lx, lq * 8);
#pragma unroll
                    for (int n3 = 0; n3 < 4; ++n3)
                        acc3[cc][n3] = MFMA(af, bW[n3], acc3[cc][n3]);
                }
            }
#pragma unroll
            for (int cc = 0; cc < 2; ++cc) {
                bool mpad = (p == 1) && (cc == 1) && (lq == 3);
#pragma unroll
                for (int n3 = 0; n3 < 4; ++n3) {
                    float bv = b3c[n3];
                    float s = fmaxf(acc3[cc][n3][0] + bv, 0.f) + fmaxf(acc3[cc][n3][1] + bv, 0.f)
                            + fmaxf(acc3[cc][n3][2] + bv, 0.f);
                    float s3 = fmaxf(acc3[cc][n3][3] + bv, 0.f);
                    part[n3] += s + (mpad ? 0.f : s3);
                }
            }
        }
#pragma unroll
        for (int n3 = 0; n3 < 4; ++n3) {
            part[n3] += __shfl_xor(part[n3], 16, 64);
            part[n3] += __shfl_xor(part[n3], 32, 64);
        }
        if (lq == 0) {
#pragma unroll
            for (int n3 = 0; n3 < 4; ++n3)
                L[S1RO + sidx(r, n3 * 16 + lx, 256)] = f2b(part[n3]);
        }
    }
    __syncthreads();

    // ================= phase N =================
    // fo1 -> BIG [256][128] (cols 0..63 ebar part, 64..111 xn part)
    for (int i = t; i < 32768; i += 768) {
        int ch = i >> 7, k = i & 127;
        float v = 0.f;
        if (k < 64)       v = fo1_w[ch * 112 + PP + k];
        else if (k < 112) v = fo1_w[ch * 112 + (k - 64)];
        L[BIGO + sidx(ch, k, 128)] = f2b(v);
    }
    // xn -> S1RO cols 64..127 (48 real + 16 zero); ebar already in cols 0..63
    for (int i = t; i < 4096; i += 768) {
        int n = i >> 6, k = i & 63;
        float v = (k < PP) ? x[b * PP * NN + k * NN + n] * scl[k] + bia[k] : 0.f;
        L[S1RO + sidx(n, 64 + k, 256)] = f2b(v);
    }
    __syncthreads();

    // L1N: M=256 (16 m-tiles over 12 waves), N=64 nodes, K=128 (all from S1RO)
    for (int mt = w; mt < 16; mt += 12) {
        f32x4 accN[4];
#pragma unroll
        for (int nt = 0; nt < 4; ++nt) accN[nt] = (f32x4){0.f,0.f,0.f,0.f};
#pragma unroll
        for (int ks = 0; ks < 4; ++ks) {
            bf16x8 Af = ldfrag(L + BIGO, mt * 16 + lx, ks * 32 + lq * 8, 128);
#pragma unroll
            for (int nt = 0; nt < 4; ++nt) {
                bf16x8 Bf = ldfrag(L + S1RO, nt * 16 + lx, ks * 32 + lq * 8, 256);
                accN[nt] = MFMA(Af, Bf, accN[nt]);
            }
        }
        int ch0 = mt * 16 + lq * 4;
        float4 bi = *(const float4*)(fo1_b + ch0);
#pragma unroll
        for (int nt = 0; nt < 4; ++nt)
            stAct(L + S1SO, nt * 16 + lx, ch0, 256, accN[nt], bi);
    }
    __syncthreads();   // BIG/S1RO reads done

    // fo2 -> BIG [128][256]; fo3 -> S1RO [64][128]
    for (int i = t; i < 16384; i += 768) {
        int ch = i >> 7, k2 = (i & 127) * 2;
        float2 v = *(const float2*)(fo2_w + ch * 256 + k2);
        *(unsigned*)(L + BIGO + sidx(ch, k2, 256)) = pku(v.x, v.y);
    }
    for (int i = t; i < 4096; i += 768) {
        int ch = i >> 6, k2 = (i & 63) * 2;
        float2 v = *(const float2*)(fo3_w + ch * 128 + k2);
        *(unsigned*)(L + S1RO + sidx(ch, k2, 128)) = pku(v.x, v.y);
    }
    __syncthreads();

    // L2N: M=128 (waves 0..7), N=64, K=256 -> act2N @ F3LO [64][128]
    if (w < 8) {
        f32x4 a2N[4];
#pragma unroll
        for (int nt = 0; nt < 4; ++nt) a2N[nt] = (f32x4){0.f,0.f,0.f,0.f};
#pragma unroll
        for (int ks = 0; ks < 8; ++ks) {
            bf16x8 Af = ldfrag(L + BIGO, w * 16 + lx, ks * 32 + lq * 8, 256);
#pragma unroll
            for (int nt = 0; nt < 4; ++nt) {
                bf16x8 Bf = ldfrag(L + S1SO, nt * 16 + lx, ks * 32 + lq * 8, 256);
                a2N[nt] = MFMA(Af, Bf, a2N[nt]);
            }
        }
        int ch0 = w * 16 + lq * 4;
        float4 bi = *(const float4*)(fo2_b + ch0);
#pragma unroll
        for (int nt = 0; nt < 4; ++nt)
            stAct(L + F3LO, nt * 16 + lx, ch0, 128, a2N[nt], bi);
    }
    __syncthreads();

    // L3N: M=64 (fo3 ch), N=64 nodes, K=128 (waves 0..3); relu+bias, sum over nodes
    if (w < 4) {
        f32x4 a3N[4];
#pragma unroll
        for (int nt = 0; nt < 4; ++nt) a3N[nt] = (f32x4){0.f,0.f,0.f,0.f};
#pragma unroll
        for (int ks3 = 0; ks3 < 4; ++ks3) {
            bf16x8 Af = ldfrag(L + S1RO, 16 * w + lx, ks3 * 32 + lq * 8, 128);
#pragma unroll
            for (int nt = 0; nt < 4; ++nt) {
                bf16x8 Bf = ldfrag(L + F3LO, nt * 16 + lx, ks3 * 32 + lq * 8, 128);
                a3N[nt] = MFMA(Af, Bf, a3N[nt]);
            }
        }
        float4 b3 = *(const float4*)(fo3_b + 16 * w + lq * 4);
        float o0 = 0.f, o1 = 0.f, o2 = 0.f, o3 = 0.f;
#pragma unroll
        for (int nt = 0; nt < 4; ++nt) {
            o0 += fmaxf(a3N[nt][0] + b3.x, 0.f);
            o1 += fmaxf(a3N[nt][1] + b3.y, 0.f);
            o2 += fmaxf(a3N[nt][2] + b3.z, 0.f);
            o3 += fmaxf(a3N[nt][3] + b3.w, 0.f);
        }
#pragma unroll
        for (int off = 8; off >= 1; off >>= 1) {
            o0 += __shfl_xor(o0, off, 16);
            o1 += __shfl_xor(o1, off, 16);
            o2 += __shfl_xor(o2, off, 16);
            o3 += __shfl_xor(o3, off, 16);
        }
        if (lx == 0) {
            float* red = (float*)(L + REDO);
            *(float4*)&red[16 * w + lq * 4] = make_float4(o0, o1, o2, o3);
        }
    }
    __syncthreads();

    // ---- final FCs (fp32)
    {
        float* red = (float*)(L + REDO);
        float* h1  = red + 64;
        float* h2  = red + 96;
        if (t < 25) {
            float s = fc1_b[t];
            for (int k = 0; k < 64; ++k) s += fc1_w[t * 64 + k] * red[k];
            h1[t] = s;
        }
        __syncthreads();
        if (t < 15) {
            float s = fc2_b[t];
            for (int k = 0; k < 25; ++k) s += fc2_w[t * 25 + k] * h1[k];
            h2[t] = s;
        }
        __syncthreads();
        if (t < 5) {
            float s = fc3_b[t];
            for (int k = 0; k < 15; ++k) s += fc3_w[t * 15 + k] * h2[k];
            out[b * 5 + t] = s;
        }
    }
}

extern "C" void kernel_launch(void* const* d_in, const int* in_sizes, int n_in,
                              void* d_out, int out_size, void* d_ws, size_t ws_size,
                              hipStream_t stream)
{
    const float* x        = (const float*)d_in[0];
    const float* bn_gamma = (const float*)d_in[3];
    const float* bn_beta  = (const float*)d_in[4];
    const float* fr1_w = (const float*)d_in[5];
    const float* fr1_b = (const float*)d_in[6];
    const float* fr2_w = (const float*)d_in[7];
    const float* fr2_b = (const float*)d_in[8];
    const float* fr3_w = (const float*)d_in[9];
    const float* fr3_b = (const float*)d_in[10];
    const float* fo1_w = (const float*)d_in[11];
    const float* fo1_b = (const float*)d_in[12];
    const float* fo2_w = (const float*)d_in[13];
    const float* fo2_b = (const float*)d_in[14];
    const float* fo3_w = (const float*)d_in[15];
    const float* fo3_b = (const float*)d_in[16];
    const float* fc1_w = (const float*)d_in[17];
    const float* fc1_b = (const float*)d_in[18];
    const float* fc2_w = (const float*)d_in[19];
    const float* fc2_b = (const float*)d_in[20];
    const float* fc3_w = (const float*)d_in[21];
    const float* fc3_b = (const float*)d_in[22];

    float* ws    = (float*)d_ws;
    float* scale = ws;
    float* bias  = ws + 64;
    float* out   = (float*)d_out;

    bn_stats_kernel<<<dim3(PP), dim3(256), 0, stream>>>(x, bn_gamma, bn_beta, scale, bias);
    meg_kernel<<<dim3(BB), dim3(768), 0, stream>>>(
        x, scale, bias,
        fr1_w, fr1_b, fr2_w, fr2_b, fr3_w, fr3_b,
        fo1_w, fo1_b, fo2_w, fo2_b, fo3_w, fo3_b,
        fc1_w, fc1_b, fc2_w, fc2_b, fc3_w, fc3_b, out);
}

// Round 12
// 231.743 us; speedup vs baseline: 1.2046x; 1.1068x over previous
//
#include <hip/hip_runtime.h>
#include <hip/hip_bf16.h>

#define BB 256
#define PP 48
#define NN 64
#define EPSBN 1e-5f

typedef __attribute__((ext_vector_type(8))) short bf16x8;
typedef __attribute__((ext_vector_type(4))) float f32x4;

// ---- LDS regions (ushort offsets), total 81920 ushorts = 163840 B (160 KiB) ----
// 12-wave (768-thread) layout:
#define BIGO 0       // 32768: fr1R/[+16384]fr1S -> fr2 [128][256]   | N: fo1 [256][128] -> fo2 [128][256]
#define S1SO 32768   // 16384: S1S [64][256]                          | N: act1N [64][256]
#define S1RO 49152   // 16384: S1R [64][256]; cols 0..63 ebar; N: +xn cols 64..127 -> fo3 [64][128]
#define F3LO 65536   //  8192: fr3 [64][128] (phase E B-operand)      | N: act2N [64][128]
#define A2WO 73728   //  7680: phase E: 12 waves x 640 ([16][40] stride-40)
#define XNTP 73728   //  4096: prologue xnT [64][64] (aliases A2WO; dead before phase E)
#define B2LO 81408   //   256: fr2_b as 128 floats (phase E only)
#define REDO 81664   //   256: phase-N-end red/h1/h2 floats
#define LDSE 81920

// ---- ws weight regions (ushort offsets into wsw = ws + 128 floats) ----
// prep_kernel writes bf16 weights PRE-SWIZZLED in the exact LDS layout, so
// meg staging is a pure vectorized copy (no conversion VALU, coalesced).
// NOTE (R11 fix): fr1 has 256 output channels -> fr1R/fr1S are [256][64]
// = 16384 ushorts EACH (R10 wrongly used 8192 and dropped rows 128..255).
#define W_FR1R 0        // 16384: [256][64]
#define W_FR1S 16384    // 16384: [256][64]
#define W_FR2  32768    // 32768: [128][256]
#define W_FR3  65536    //  8192: [64][128]
#define W_FO1  73728    // 32768: [256][128]
#define W_FO2  106496   // 32768: [128][256]
#define W_FO3  139264   //  8192: [64][128]
#define W_TOT  147456

union U8 { bf16x8 v; unsigned u[4]; };

__device__ __forceinline__ unsigned pku(float a, float b) {
    union { __hip_bfloat162 h; unsigned u; } cv;
    cv.h = __float22bfloat162_rn(make_float2(a, b));
    return cv.u;
}
__device__ __forceinline__ ushort f2b(float f) {
    union { float f; unsigned u; } a; a.f = f;
    unsigned u = a.u + 0x7FFFu + ((a.u >> 16) & 1u);
    return (ushort)(u >> 16);
}
__device__ __forceinline__ float loF(unsigned u) { union { unsigned x; float f; } c; c.x = u << 16; return c.f; }
__device__ __forceinline__ float hiF(unsigned u) { union { unsigned x; float f; } c; c.x = u & 0xffff0000u; return c.f; }

__device__ __forceinline__ int sidx(int row, int k, int kpad) {
    return row * kpad + ((((k >> 3) ^ (row & 7)) << 3) | (k & 7));
}
__device__ __forceinline__ bf16x8 ldfrag(const ushort* buf, int row, int k, int kpad) {
    return *(const bf16x8*)(buf + row * kpad + (((k >> 3) ^ (row & 7)) << 3));
}
// [16][40] wave-private buffer: 80 B row stride spreads rows over banks (~2-way)
__device__ __forceinline__ bf16x8 ldfrag40(const ushort* buf, int row, int k) {
    return *(const bf16x8*)(buf + row * 40 + k);
}
__device__ __forceinline__ f32x4 MFMA(bf16x8 a, bf16x8 b, f32x4 c) {
    return __builtin_amdgcn_mfma_f32_16x16x32_bf16(a, b, c, 0, 0, 0);
}
__device__ __forceinline__ void stAct(ushort* buf, int row, int c0, int kpad, f32x4 a, float4 bi) {
    uint2 o;
    o.x = pku(fmaxf(a[0] + bi.x, 0.f), fmaxf(a[1] + bi.y, 0.f));
    o.y = pku(fmaxf(a[2] + bi.z, 0.f), fmaxf(a[3] + bi.w, 0.f));
    *(uint2*)(buf + row * kpad + ((((c0 >> 3) ^ (row & 7)) << 3) | (c0 & 7))) = o;
}
// bias folded into accumulator init: store relu(acc); stride-40 variant
__device__ __forceinline__ void stAct040(ushort* buf, int row, int c0, f32x4 a) {
    uint2 o;
    o.x = pku(fmaxf(a[0], 0.f), fmaxf(a[1], 0.f));
    o.y = pku(fmaxf(a[2], 0.f), fmaxf(a[3], 0.f));
    *(uint2*)(buf + row * 40 + c0) = o;
}
__device__ __forceinline__ void stRaw(ushort* buf, int row, int c0, int kpad, f32x4 a, float4 bi) {
    uint2 o;
    o.x = pku(a[0] + bi.x, a[1] + bi.y);
    o.y = pku(a[2] + bi.z, a[3] + bi.w);
    *(uint2*)(buf + row * kpad + ((((c0 >> 3) ^ (row & 7)) << 3) | (c0 & 7))) = o;
}

// ---------------- batchnorm stats ----------------
__global__ __launch_bounds__(256) void bn_stats_kernel(
    const float* __restrict__ x, const float* __restrict__ gamma,
    const float* __restrict__ beta, float* __restrict__ scale, float* __restrict__ bias)
{
    __shared__ float s_sum[256], s_sq[256];
    int p = blockIdx.x, t = threadIdx.x;
    float sum = 0.f, sq = 0.f;
    for (int i = t; i < BB * NN; i += 256) {
        int b = i >> 6, n = i & 63;
        float v = x[b * PP * NN + p * NN + n];
        sum += v; sq += v * v;
    }
    s_sum[t] = sum; s_sq[t] = sq;
    __syncthreads();
    for (int off = 128; off > 0; off >>= 1) {
        if (t < off) { s_sum[t] += s_sum[t + off]; s_sq[t] += s_sq[t + off]; }
        __syncthreads();
    }
    if (t == 0) {
        float inv = 1.f / (float)(BB * NN);
        float mean = s_sum[0] * inv;
        float var  = s_sq[0] * inv - mean * mean;
        float sc   = gamma[p] * rsqrtf(var + EPSBN);
        scale[p] = sc;
        bias[p]  = beta[p] - mean * sc;
    }
}

// ---------------- weight prep: f32 -> bf16, pre-swizzled LDS layout ----------------
__global__ __launch_bounds__(512) void prep_kernel(
    const float* __restrict__ fr1_w, const float* __restrict__ fr2_w,
    const float* __restrict__ fr3_w, const float* __restrict__ fo1_w,
    const float* __restrict__ fo2_w, const float* __restrict__ fo3_w,
    ushort* __restrict__ wsw)
{
    int i = blockIdx.x * 512 + threadIdx.x;
    if (i >= W_TOT) return;
    float v; int off, row, k, kpad;
    if (i < 16384)        { row = i >> 6; k = i & 63; kpad = 64;  off = W_FR1R;
                            v = (k < PP) ? fr1_w[row * 96 + k] : 0.f; }
    else if (i < 32768)   { int j = i - 16384;  row = j >> 6; k = j & 63;  kpad = 64;  off = W_FR1S;
                            v = (k < PP) ? fr1_w[row * 96 + PP + k] : 0.f; }
    else if (i < 65536)   { int j = i - 32768;  row = j >> 8; k = j & 255; kpad = 256; off = W_FR2;
                            v = fr2_w[row * 256 + k]; }
    else if (i < 73728)   { int j = i - 65536;  row = j >> 7; k = j & 127; kpad = 128; off = W_FR3;
                            v = fr3_w[row * 128 + k]; }
    else if (i < 106496)  { int j = i - 73728;  row = j >> 7; k = j & 127; kpad = 128; off = W_FO1;
                            v = (k < 64) ? fo1_w[row * 112 + PP + k]
                              : (k < 112 ? fo1_w[row * 112 + (k - 64)] : 0.f); }
    else if (i < 139264)  { int j = i - 106496; row = j >> 8; k = j & 255; kpad = 256; off = W_FO2;
                            v = fo2_w[row * 256 + k]; }
    else                  { int j = i - 139264; row = j >> 7; k = j & 127; kpad = 128; off = W_FO3;
                            v = fo3_w[row * 128 + k]; }
    wsw[off + sidx(row, k, kpad)] = f2b(v);
}

// copy n ushorts (layout-identical) ws -> LDS, uint4-vectorized, 768 threads
__device__ __forceinline__ void wcopy(ushort* dst, const ushort* src, int n, int t) {
    for (int i = t * 8; i < n; i += 768 * 8)
        *(uint4*)(dst + i) = *(const uint4*)(src + i);
}

// ---------------- mega kernel: one block per batch, 12 waves (3/SIMD) ----------------
// R11 = R10 with corrected fr1 sizes (16384 each). Structure: R9 champion
// compute phases + weight conversion hoisted into prep_kernel; meg staging is
// pure coalesced uint4 copies; xnT x-reads coalesced (n fastest-varying).
__global__ __launch_bounds__(768, 3) void meg_kernel(
    const float* __restrict__ x,
    const float* __restrict__ scl, const float* __restrict__ bia,
    const ushort* __restrict__ wsw,
    const float* __restrict__ fr1_b, const float* __restrict__ fr2_b,
    const float* __restrict__ fr3_b, const float* __restrict__ fo1_b,
    const float* __restrict__ fo2_b, const float* __restrict__ fo3_b,
    const float* __restrict__ fc1_w, const float* __restrict__ fc1_b,
    const float* __restrict__ fc2_w, const float* __restrict__ fc2_b,
    const float* __restrict__ fc3_w, const float* __restrict__ fc3_b,
    float* __restrict__ out)
{
    __shared__ __align__(16) ushort L[LDSE];

    int b = blockIdx.x, t = threadIdx.x;
    int w = t >> 6, l = t & 63, lx = l & 15, lq = l >> 4;

    // ---- xnT [64][64] (cols 48..63 zero) @ XNTP; coalesced x reads (n fastest)
    for (int i = t; i < 4096; i += 768) {
        int n = i & 63, k = i >> 6;
        float v = (k < PP) ? x[b * PP * NN + k * NN + n] * scl[k] + bia[k] : 0.f;
        L[XNTP + sidx(n, k, 64)] = f2b(v);
    }
    // ---- fr1R/fr1S/fr3: pure copies from pre-swizzled ws
    wcopy(L + BIGO,         wsw + W_FR1R, 16384, t);
    wcopy(L + BIGO + 16384, wsw + W_FR1S, 16384, t);
    wcopy(L + F3LO,         wsw + W_FR3,  8192, t);
    // ---- fr2 bias table -> B2LO (128 floats)
    if (t < 128) ((float*)(L + B2LO))[t] = fr2_b[t];
    __syncthreads();

    // ---- GEMM1+2 fused: S1R = fr1R.xn + b1, S1S = fr1S.xn (16 m-tiles over 12 waves)
    for (int mt = w; mt < 16; mt += 12) {
        f32x4 aR[4], aS[4];
#pragma unroll
        for (int nt = 0; nt < 4; ++nt) { aR[nt] = (f32x4){0.f,0.f,0.f,0.f}; aS[nt] = (f32x4){0.f,0.f,0.f,0.f}; }
#pragma unroll
        for (int ks = 0; ks < 2; ++ks) {
            bf16x8 AfR = ldfrag(L + BIGO,         mt * 16 + lx, ks * 32 + lq * 8, 64);
            bf16x8 AfS = ldfrag(L + BIGO + 16384, mt * 16 + lx, ks * 32 + lq * 8, 64);
#pragma unroll
            for (int nt = 0; nt < 4; ++nt) {
                bf16x8 Bf = ldfrag(L + XNTP, nt * 16 + lx, ks * 32 + lq * 8, 64);
                aR[nt] = MFMA(AfR, Bf, aR[nt]);
                aS[nt] = MFMA(AfS, Bf, aS[nt]);
            }
        }
        int ch0 = mt * 16 + lq * 4;
        float4 bi = *(const float4*)(fr1_b + ch0);
        float4 zb = make_float4(0.f, 0.f, 0.f, 0.f);
#pragma unroll
        for (int nt = 0; nt < 4; ++nt) {
            stRaw(L + S1RO, nt * 16 + lx, ch0, 256, aR[nt], bi);
            stRaw(L + S1SO, nt * 16 + lx, ch0, 256, aS[nt], zb);
        }
    }
    __syncthreads();   // BIG/XNTP reads done; restage fr2 below

    // ---- fr2 -> BIG (pure copy)
    wcopy(L + BIGO, wsw + W_FR2, 32768, t);
    float b3c[4];
#pragma unroll
    for (int n3 = 0; n3 < 4; ++n3) b3c[n3] = fr3_b[n3 * 16 + lx];
    __syncthreads();

    // ================= phase E: receivers strided over 12 waves, zero barriers =================
    ushort* a2w = L + A2WO + w * 640;     // wave-private [16][40]
    const float* b2L = (const float*)(L + B2LO);
#pragma unroll 1
    for (int r = w; r < 64; r += 12) {
        float part[4] = {0.f, 0.f, 0.f, 0.f};
#pragma unroll 1
        for (int p = 0; p < 2; ++p) {
            int eA = p * 32 + lx, eB = eA + 16;
            int sA = eA + (eA >= r);
            int sB = eB + (eB >= r); if (sB > 63) sB = 63;   // pad edge 63

            f32x4 acc2[8][2];
#pragma unroll
            for (int m = 0; m < 8; ++m) {
                // fr2 bias from LDS table: one broadcast read per m
                float4 bv = *(const float4*)(b2L + m * 16 + lq * 4);
                f32x4 bi; bi[0] = bv.x; bi[1] = bv.y; bi[2] = bv.z; bi[3] = bv.w;
                acc2[m][0] = bi; acc2[m][1] = bi;
            }
#pragma unroll
            for (int ks = 0; ks < 8; ++ks) {
                int ko = ks * 32 + lq * 8;
                U8 fr, fa, fb;
                fr.v = ldfrag(L + S1RO, r,  ko, 256);   // wave-uniform row: broadcast
                fa.v = ldfrag(L + S1SO, sA, ko, 256);
                fb.v = ldfrag(L + S1SO, sB, ko, 256);
                U8 bA, bB;
#pragma unroll
                for (int jj = 0; jj < 4; ++jj) {
                    float r0 = loF(fr.u[jj]), r1 = hiF(fr.u[jj]);
                    bA.u[jj] = pku(fmaxf(r0 + loF(fa.u[jj]), 0.f), fmaxf(r1 + hiF(fa.u[jj]), 0.f));
                    bB.u[jj] = pku(fmaxf(r0 + loF(fb.u[jj]), 0.f), fmaxf(r1 + hiF(fb.u[jj]), 0.f));
                }
#pragma unroll
                for (int m = 0; m < 8; ++m) {
                    bf16x8 Af = ldfrag(L + BIGO, m * 16 + lx, ko, 256);
                    acc2[m][0] = MFMA(Af, bA.v, acc2[m][0]);
                    acc2[m][1] = MFMA(Af, bB.v, acc2[m][1]);
                }
            }
            // ---- epilogue: fr3 GEMM through [16][40] quarters, h-outer so each
            // bW[4] load serves both cc halves
            f32x4 acc3[2][4];
#pragma unroll
            for (int cc = 0; cc < 2; ++cc)
#pragma unroll
                for (int n3 = 0; n3 < 4; ++n3) acc3[cc][n3] = (f32x4){0.f,0.f,0.f,0.f};
#pragma unroll
            for (int h = 0; h < 4; ++h) {
                bf16x8 bW[4];
#pragma unroll
                for (int n3 = 0; n3 < 4; ++n3)
                    bW[n3] = ldfrag(L + F3LO, n3 * 16 + lx, h * 32 + lq * 8, 128);
#pragma unroll
                for (int cc = 0; cc < 2; ++cc) {
                    stAct040(a2w, lx, lq * 4,      acc2[2 * h][cc]);
                    stAct040(a2w, lx, 16 + lq * 4, acc2[2 * h + 1][cc]);
                    bf16x8 af = ldfrag40(a2w, lx, lq * 8);
#pragma unroll
                    for (int n3 = 0; n3 < 4; ++n3)
                        acc3[cc][n3] = MFMA(af, bW[n3], acc3[cc][n3]);
                }
            }
#pragma unroll
            for (int cc = 0; cc < 2; ++cc) {
                bool mpad = (p == 1) && (cc == 1) && (lq == 3);
#pragma unroll
                for (int n3 = 0; n3 < 4; ++n3) {
                    float bv = b3c[n3];
                    float s = fmaxf(acc3[cc][n3][0] + bv, 0.f) + fmaxf(acc3[cc][n3][1] + bv, 0.f)
                            + fmaxf(acc3[cc][n3][2] + bv, 0.f);
                    float s3 = fmaxf(acc3[cc][n3][3] + bv, 0.f);
                    part[n3] += s + (mpad ? 0.f : s3);
                }
            }
        }
#pragma unroll
        for (int n3 = 0; n3 < 4; ++n3) {
            part[n3] += __shfl_xor(part[n3], 16, 64);
            part[n3] += __shfl_xor(part[n3], 32, 64);
        }
        if (lq == 0) {
#pragma unroll
            for (int n3 = 0; n3 < 4; ++n3)
                L[S1RO + sidx(r, n3 * 16 + lx, 256)] = f2b(part[n3]);
        }
    }
    __syncthreads();

    // ================= phase N =================
    // fo1 -> BIG (pure copy)
    wcopy(L + BIGO, wsw + W_FO1, 32768, t);
    // xn -> S1RO cols 64..127 (48 real + 16 zero); coalesced x reads
    for (int i = t; i < 4096; i += 768) {
        int n = i & 63, k = i >> 6;
        float v = (k < PP) ? x[b * PP * NN + k * NN + n] * scl[k] + bia[k] : 0.f;
        L[S1RO + sidx(n, 64 + k, 256)] = f2b(v);
    }
    __syncthreads();

    // L1N: M=256 (16 m-tiles over 12 waves), N=64 nodes, K=128 (all from S1RO)
    for (int mt = w; mt < 16; mt += 12) {
        f32x4 accN[4];
#pragma unroll
        for (int nt = 0; nt < 4; ++nt) accN[nt] = (f32x4){0.f,0.f,0.f,0.f};
#pragma unroll
        for (int ks = 0; ks < 4; ++ks) {
            bf16x8 Af = ldfrag(L + BIGO, mt * 16 + lx, ks * 32 + lq * 8, 128);
#pragma unroll
            for (int nt = 0; nt < 4; ++nt) {
                bf16x8 Bf = ldfrag(L + S1RO, nt * 16 + lx, ks * 32 + lq * 8, 256);
                accN[nt] = MFMA(Af, Bf, accN[nt]);
            }
        }
        int ch0 = mt * 16 + lq * 4;
        float4 bi = *(const float4*)(fo1_b + ch0);
#pragma unroll
        for (int nt = 0; nt < 4; ++nt)
            stAct(L + S1SO, nt * 16 + lx, ch0, 256, accN[nt], bi);
    }
    __syncthreads();   // BIG/S1RO reads done

    // fo2 -> BIG, fo3 -> S1RO (pure copies)
    wcopy(L + BIGO, wsw + W_FO2, 32768, t);
    wcopy(L + S1RO, wsw + W_FO3, 8192, t);
    __syncthreads();

    // L2N: M=128 (waves 0..7), N=64, K=256 -> act2N @ F3LO [64][128]
    if (w < 8) {
        f32x4 a2N[4];
#pragma unroll
        for (int nt = 0; nt < 4; ++nt) a2N[nt] = (f32x4){0.f,0.f,0.f,0.f};
#pragma unroll
        for (int ks = 0; ks < 8; ++ks) {
            bf16x8 Af = ldfrag(L + BIGO, w * 16 + lx, ks * 32 + lq * 8, 256);
#pragma unroll
            for (int nt = 0; nt < 4; ++nt) {
                bf16x8 Bf = ldfrag(L + S1SO, nt * 16 + lx, ks * 32 + lq * 8, 256);
                a2N[nt] = MFMA(Af, Bf, a2N[nt]);
            }
        }
        int ch0 = w * 16 + lq * 4;
        float4 bi = *(const float4*)(fo2_b + ch0);
#pragma unroll
        for (int nt = 0; nt < 4; ++nt)
            stAct(L + F3LO, nt * 16 + lx, ch0, 128, a2N[nt], bi);
    }
    __syncthreads();

    // L3N: M=64 (fo3 ch), N=64 nodes, K=128 (waves 0..3); relu+bias, sum over nodes
    if (w < 4) {
        f32x4 a3N[4];
#pragma unroll
        for (int nt = 0; nt < 4; ++nt) a3N[nt] = (f32x4){0.f,0.f,0.f,0.f};
#pragma unroll
        for (int ks3 = 0; ks3 < 4; ++ks3) {
            bf16x8 Af = ldfrag(L + S1RO, 16 * w + lx, ks3 * 32 + lq * 8, 128);
#pragma unroll
            for (int nt = 0; nt < 4; ++nt) {
                bf16x8 Bf = ldfrag(L + F3LO, nt * 16 + lx, ks3 * 32 + lq * 8, 128);
                a3N[nt] = MFMA(Af, Bf, a3N[nt]);
            }
        }
        float4 b3 = *(const float4*)(fo3_b + 16 * w + lq * 4);
        float o0 = 0.f, o1 = 0.f, o2 = 0.f, o3 = 0.f;
#pragma unroll
        for (int nt = 0; nt < 4; ++nt) {
            o0 += fmaxf(a3N[nt][0] + b3.x, 0.f);
            o1 += fmaxf(a3N[nt][1] + b3.y, 0.f);
            o2 += fmaxf(a3N[nt][2] + b3.z, 0.f);
            o3 += fmaxf(a3N[nt][3] + b3.w, 0.f);
        }
#pragma unroll
        for (int off = 8; off >= 1; off >>= 1) {
            o0 += __shfl_xor(o0, off, 16);
            o1 += __shfl_xor(o1, off, 16);
            o2 += __shfl_xor(o2, off, 16);
            o3 += __shfl_xor(o3, off, 16);
        }
        if (lx == 0) {
            float* red = (float*)(L + REDO);
            *(float4*)&red[16 * w + lq * 4] = make_float4(o0, o1, o2, o3);
        }
    }
    __syncthreads();

    // ---- final FCs (fp32)
    {
        float* red = (float*)(L + REDO);
        float* h1  = red + 64;
        float* h2  = red + 96;
        if (t < 25) {
            float s = fc1_b[t];
            for (int k = 0; k < 64; ++k) s += fc1_w[t * 64 + k] * red[k];
            h1[t] = s;
        }
        __syncthreads();
        if (t < 15) {
            float s = fc2_b[t];
            for (int k = 0; k < 25; ++k) s += fc2_w[t * 25 + k] * h1[k];
            h2[t] = s;
        }
        __syncthreads();
        if (t < 5) {
            float s = fc3_b[t];
            for (int k = 0; k < 15; ++k) s += fc3_w[t * 15 + k] * h2[k];
            out[b * 5 + t] = s;
        }
    }
}

extern "C" void kernel_launch(void* const* d_in, const int* in_sizes, int n_in,
                              void* d_out, int out_size, void* d_ws, size_t ws_size,
                              hipStream_t stream)
{
    const float* x        = (const float*)d_in[0];
    const float* bn_gamma = (const float*)d_in[3];
    const float* bn_beta  = (const float*)d_in[4];
    const float* fr1_w = (const float*)d_in[5];
    const float* fr1_b = (const float*)d_in[6];
    const float* fr2_w = (const float*)d_in[7];
    const float* fr2_b = (const float*)d_in[8];
    const float* fr3_w = (const float*)d_in[9];
    const float* fr3_b = (const float*)d_in[10];
    const float* fo1_w = (const float*)d_in[11];
    const float* fo1_b = (const float*)d_in[12];
    const float* fo2_w = (const float*)d_in[13];
    const float* fo2_b = (const float*)d_in[14];
    const float* fo3_w = (const float*)d_in[15];
    const float* fo3_b = (const float*)d_in[16];
    const float* fc1_w = (const float*)d_in[17];
    const float* fc1_b = (const float*)d_in[18];
    const float* fc2_w = (const float*)d_in[19];
    const float* fc2_b = (const float*)d_in[20];
    const float* fc3_w = (const float*)d_in[21];
    const float* fc3_b = (const float*)d_in[22];

    float* ws    = (float*)d_ws;
    float* scale = ws;
    float* bias  = ws + 64;
    ushort* wsw  = (ushort*)(ws + 128);   // 147456 ushorts = 288 KB of bf16 weights
    float* out   = (float*)d_out;

    bn_stats_kernel<<<dim3(PP), dim3(256), 0, stream>>>(x, bn_gamma, bn_beta, scale, bias);
    prep_kernel<<<dim3(W_TOT / 512), dim3(512), 0, stream>>>(
        fr1_w, fr2_w, fr3_w, fo1_w, fo2_w, fo3_w, wsw);
    meg_kernel<<<dim3(BB), dim3(768), 0, stream>>>(
        x, scale, bias, wsw,
        fr1_b, fr2_b, fr3_b, fo1_b, fo2_b, fo3_b,
        fc1_w, fc1_b, fc2_w, fc2_b, fc3_w, fc3_b, out);
}

// Round 13
// 225.226 us; speedup vs baseline: 1.2394x; 1.0289x over previous
//
#include <hip/hip_runtime.h>
#include <hip/hip_bf16.h>

#define BB 256
#define PP 48
#define NN 64
#define EPSBN 1e-5f

typedef __attribute__((ext_vector_type(8))) short bf16x8;
typedef __attribute__((ext_vector_type(4))) float f32x4;

// ---- LDS regions (ushort offsets), total 81920 ushorts = 163840 B (160 KiB) ----
// 12-wave (768-thread) layout:
#define BIGO 0       // 32768: fr1R/[+16384]fr1S -> fr2 [128][256]   | N: fo1 [256][128] -> fo2 [128][256]
#define S1SO 32768   // 16384: S1S [64][256]                          | N: act1N [64][256]
#define S1RO 49152   // 16384: S1R [64][256]; cols 0..63 ebar         | N: fo3 [64][128]
#define F3LO 65536   //  8192: fr3 [64][128] (phase E B-operand)      | N: act2N [64][128]
#define A2WO 73728   //  7680: phase E: 12 waves x 640 ([16][40] stride-40)
#define XNTP 73728   //  4096: xnT [64][64] (prologue GEMM1 + phase-N L1N; clobbered by a2w in phase E)
#define B2LO 81408   //   256: fr2_b as 128 floats (phase E only)
#define REDO 81664   //   256: phase-N-end red/h1/h2 floats
#define LDSE 81920

// ---- ws regions (ushort offsets into wsw = ws + 128 floats) ----
// prep_kernel writes bf16 weights AND per-batch xnT PRE-SWIZZLED in the exact
// LDS layout, so meg staging is pure vectorized copies (no conversion VALU).
#define W_FR1R 0        // 16384: [256][64]
#define W_FR1S 16384    // 16384: [256][64]
#define W_FR2  32768    // 32768: [128][256]
#define W_FR3  65536    //  8192: [64][128]
#define W_FO1  73728    // 32768: [256][128]
#define W_FO2  106496   // 32768: [128][256]
#define W_FO3  139264   //  8192: [64][128]
#define W_TOT  147456
#define W_XNT  147456   // 256 x 4096: per-batch xnT [64][64]-swizzled bf16
#define W_ALL  (W_XNT + BB * 4096)   // 1196032 ushorts ~ 2.4 MB total ws use

union U8 { bf16x8 v; unsigned u[4]; };

__device__ __forceinline__ unsigned pku(float a, float b) {
    union { __hip_bfloat162 h; unsigned u; } cv;
    cv.h = __float22bfloat162_rn(make_float2(a, b));
    return cv.u;
}
__device__ __forceinline__ ushort f2b(float f) {
    union { float f; unsigned u; } a; a.f = f;
    unsigned u = a.u + 0x7FFFu + ((a.u >> 16) & 1u);
    return (ushort)(u >> 16);
}
__device__ __forceinline__ float loF(unsigned u) { union { unsigned x; float f; } c; c.x = u << 16; return c.f; }
__device__ __forceinline__ float hiF(unsigned u) { union { unsigned x; float f; } c; c.x = u & 0xffff0000u; return c.f; }

__device__ __forceinline__ int sidx(int row, int k, int kpad) {
    return row * kpad + ((((k >> 3) ^ (row & 7)) << 3) | (k & 7));
}
__device__ __forceinline__ bf16x8 ldfrag(const ushort* buf, int row, int k, int kpad) {
    return *(const bf16x8*)(buf + row * kpad + (((k >> 3) ^ (row & 7)) << 3));
}
// [16][40] wave-private buffer: 80 B row stride spreads rows over banks (~2-way)
__device__ __forceinline__ bf16x8 ldfrag40(const ushort* buf, int row, int k) {
    return *(const bf16x8*)(buf + row * 40 + k);
}
__device__ __forceinline__ f32x4 MFMA(bf16x8 a, bf16x8 b, f32x4 c) {
    return __builtin_amdgcn_mfma_f32_16x16x32_bf16(a, b, c, 0, 0, 0);
}
__device__ __forceinline__ void stAct(ushort* buf, int row, int c0, int kpad, f32x4 a, float4 bi) {
    uint2 o;
    o.x = pku(fmaxf(a[0] + bi.x, 0.f), fmaxf(a[1] + bi.y, 0.f));
    o.y = pku(fmaxf(a[2] + bi.z, 0.f), fmaxf(a[3] + bi.w, 0.f));
    *(uint2*)(buf + row * kpad + ((((c0 >> 3) ^ (row & 7)) << 3) | (c0 & 7))) = o;
}
// bias folded into accumulator init: store relu(acc); stride-40 variant
__device__ __forceinline__ void stAct040(ushort* buf, int row, int c0, f32x4 a) {
    uint2 o;
    o.x = pku(fmaxf(a[0], 0.f), fmaxf(a[1], 0.f));
    o.y = pku(fmaxf(a[2], 0.f), fmaxf(a[3], 0.f));
    *(uint2*)(buf + row * 40 + c0) = o;
}
__device__ __forceinline__ void stRaw(ushort* buf, int row, int c0, int kpad, f32x4 a, float4 bi) {
    uint2 o;
    o.x = pku(a[0] + bi.x, a[1] + bi.y);
    o.y = pku(a[2] + bi.z, a[3] + bi.w);
    *(uint2*)(buf + row * kpad + ((((c0 >> 3) ^ (row & 7)) << 3) | (c0 & 7))) = o;
}

// ---------------- batchnorm stats (1024 threads: 16 latency iters, was 64) ----------------
__global__ __launch_bounds__(1024) void bn_stats_kernel(
    const float* __restrict__ x, const float* __restrict__ gamma,
    const float* __restrict__ beta, float* __restrict__ scale, float* __restrict__ bias)
{
    __shared__ float s_sum[1024], s_sq[1024];
    int p = blockIdx.x, t = threadIdx.x;
    float sum = 0.f, sq = 0.f;
    for (int i = t; i < BB * NN; i += 1024) {
        int b = i >> 6, n = i & 63;
        float v = x[b * PP * NN + p * NN + n];
        sum += v; sq += v * v;
    }
    s_sum[t] = sum; s_sq[t] = sq;
    __syncthreads();
    for (int off = 512; off > 0; off >>= 1) {
        if (t < off) { s_sum[t] += s_sum[t + off]; s_sq[t] += s_sq[t + off]; }
        __syncthreads();
    }
    if (t == 0) {
        float inv = 1.f / (float)(BB * NN);
        float mean = s_sum[0] * inv;
        float var  = s_sq[0] * inv - mean * mean;
        float sc   = gamma[p] * rsqrtf(var + EPSBN);
        scale[p] = sc;
        bias[p]  = beta[p] - mean * sc;
    }
}

// ---------------- prep: weights f32->bf16 pre-swizzled + per-batch xnT ----------------
// Launched AFTER bn_stats (xn needs scale/bias).
__global__ __launch_bounds__(512) void prep_kernel(
    const float* __restrict__ fr1_w, const float* __restrict__ fr2_w,
    const float* __restrict__ fr3_w, const float* __restrict__ fo1_w,
    const float* __restrict__ fo2_w, const float* __restrict__ fo3_w,
    const float* __restrict__ x, const float* __restrict__ scale,
    const float* __restrict__ bias, ushort* __restrict__ wsw)
{
    int i = blockIdx.x * 512 + threadIdx.x;
    if (i >= W_ALL) return;
    if (i >= W_TOT) {
        // xnT: per batch b, [64][64]-pad swizzled (cols 48..63 zero)
        int j = i - W_XNT;
        int b = j >> 12, nk = j & 4095, n = nk & 63, k = nk >> 6;
        float v = (k < PP) ? x[b * PP * NN + k * NN + n] * scale[k] + bias[k] : 0.f;
        wsw[W_XNT + (b << 12) + sidx(n, k, 64)] = f2b(v);
        return;
    }
    float v; int off, row, k, kpad;
    if (i < 16384)        { row = i >> 6; k = i & 63; kpad = 64;  off = W_FR1R;
                            v = (k < PP) ? fr1_w[row * 96 + k] : 0.f; }
    else if (i < 32768)   { int j = i - 16384;  row = j >> 6; k = j & 63;  kpad = 64;  off = W_FR1S;
                            v = (k < PP) ? fr1_w[row * 96 + PP + k] : 0.f; }
    else if (i < 65536)   { int j = i - 32768;  row = j >> 8; k = j & 255; kpad = 256; off = W_FR2;
                            v = fr2_w[row * 256 + k]; }
    else if (i < 73728)   { int j = i - 65536;  row = j >> 7; k = j & 127; kpad = 128; off = W_FR3;
                            v = fr3_w[row * 128 + k]; }
    else if (i < 106496)  { int j = i - 73728;  row = j >> 7; k = j & 127; kpad = 128; off = W_FO1;
                            v = (k < 64) ? fo1_w[row * 112 + PP + k]
                              : (k < 112 ? fo1_w[row * 112 + (k - 64)] : 0.f); }
    else if (i < 139264)  { int j = i - 106496; row = j >> 8; k = j & 255; kpad = 256; off = W_FO2;
                            v = fo2_w[row * 256 + k]; }
    else                  { int j = i - 139264; row = j >> 7; k = j & 127; kpad = 128; off = W_FO3;
                            v = fo3_w[row * 128 + k]; }
    wsw[off + sidx(row, k, kpad)] = f2b(v);
}

// copy n ushorts (layout-identical) ws -> LDS, uint4-vectorized, 768 threads
__device__ __forceinline__ void wcopy(ushort* dst, const ushort* src, int n, int t) {
    for (int i = t * 8; i < n; i += 768 * 8)
        *(uint4*)(dst + i) = *(const uint4*)(src + i);
}

// ---------------- mega kernel: one block per batch, 12 waves (3/SIMD) ----------------
// R12 = R11 champion compute phases, with: xnT precomputed in prep (meg never
// reads x/scl/bia; both xnT stagings are pure wcopy); phase-N L1N reverts to
// the R7 split-source form (ebar from S1RO cols 0..63, xn from XNTP region,
// re-copied after phase E since a2w clobbers it); FC tail wave-parallelized
// (64-lane dot + shfl reduce per output, was <=25 serial threads).
__global__ __launch_bounds__(768, 3) void meg_kernel(
    const ushort* __restrict__ wsw,
    const float* __restrict__ fr1_b, const float* __restrict__ fr2_b,
    const float* __restrict__ fr3_b, const float* __restrict__ fo1_b,
    const float* __restrict__ fo2_b, const float* __restrict__ fo3_b,
    const float* __restrict__ fc1_w, const float* __restrict__ fc1_b,
    const float* __restrict__ fc2_w, const float* __restrict__ fc2_b,
    const float* __restrict__ fc3_w, const float* __restrict__ fc3_b,
    float* __restrict__ out)
{
    __shared__ __align__(16) ushort L[LDSE];

    int b = blockIdx.x, t = threadIdx.x;
    int w = t >> 6, l = t & 63, lx = l & 15, lq = l >> 4;

    // ---- prologue staging: pure copies from pre-swizzled ws
    wcopy(L + XNTP,         wsw + W_XNT + (b << 12), 4096, t);
    wcopy(L + BIGO,         wsw + W_FR1R, 16384, t);
    wcopy(L + BIGO + 16384, wsw + W_FR1S, 16384, t);
    wcopy(L + F3LO,         wsw + W_FR3,  8192, t);
    if (t < 128) ((float*)(L + B2LO))[t] = fr2_b[t];
    __syncthreads();

    // ---- GEMM1+2 fused: S1R = fr1R.xn + b1, S1S = fr1S.xn (16 m-tiles over 12 waves)
    for (int mt = w; mt < 16; mt += 12) {
        f32x4 aR[4], aS[4];
#pragma unroll
        for (int nt = 0; nt < 4; ++nt) { aR[nt] = (f32x4){0.f,0.f,0.f,0.f}; aS[nt] = (f32x4){0.f,0.f,0.f,0.f}; }
#pragma unroll
        for (int ks = 0; ks < 2; ++ks) {
            bf16x8 AfR = ldfrag(L + BIGO,         mt * 16 + lx, ks * 32 + lq * 8, 64);
            bf16x8 AfS = ldfrag(L + BIGO + 16384, mt * 16 + lx, ks * 32 + lq * 8, 64);
#pragma unroll
            for (int nt = 0; nt < 4; ++nt) {
                bf16x8 Bf = ldfrag(L + XNTP, nt * 16 + lx, ks * 32 + lq * 8, 64);
                aR[nt] = MFMA(AfR, Bf, aR[nt]);
                aS[nt] = MFMA(AfS, Bf, aS[nt]);
            }
        }
        int ch0 = mt * 16 + lq * 4;
        float4 bi = *(const float4*)(fr1_b + ch0);
        float4 zb = make_float4(0.f, 0.f, 0.f, 0.f);
#pragma unroll
        for (int nt = 0; nt < 4; ++nt) {
            stRaw(L + S1RO, nt * 16 + lx, ch0, 256, aR[nt], bi);
            stRaw(L + S1SO, nt * 16 + lx, ch0, 256, aS[nt], zb);
        }
    }
    __syncthreads();   // BIG/XNTP reads done; restage fr2 below

    // ---- fr2 -> BIG (pure copy)
    wcopy(L + BIGO, wsw + W_FR2, 32768, t);
    float b3c[4];
#pragma unroll
    for (int n3 = 0; n3 < 4; ++n3) b3c[n3] = fr3_b[n3 * 16 + lx];
    __syncthreads();

    // ================= phase E: receivers strided over 12 waves, zero barriers =================
    ushort* a2w = L + A2WO + w * 640;     // wave-private [16][40]
    const float* b2L = (const float*)(L + B2LO);
#pragma unroll 1
    for (int r = w; r < 64; r += 12) {
        float part[4] = {0.f, 0.f, 0.f, 0.f};
#pragma unroll 1
        for (int p = 0; p < 2; ++p) {
            int eA = p * 32 + lx, eB = eA + 16;
            int sA = eA + (eA >= r);
            int sB = eB + (eB >= r); if (sB > 63) sB = 63;   // pad edge 63

            f32x4 acc2[8][2];
#pragma unroll
            for (int m = 0; m < 8; ++m) {
                // fr2 bias from LDS table: one broadcast read per m
                float4 bv = *(const float4*)(b2L + m * 16 + lq * 4);
                f32x4 bi; bi[0] = bv.x; bi[1] = bv.y; bi[2] = bv.z; bi[3] = bv.w;
                acc2[m][0] = bi; acc2[m][1] = bi;
            }
#pragma unroll
            for (int ks = 0; ks < 8; ++ks) {
                int ko = ks * 32 + lq * 8;
                U8 fr, fa, fb;
                fr.v = ldfrag(L + S1RO, r,  ko, 256);   // wave-uniform row: broadcast
                fa.v = ldfrag(L + S1SO, sA, ko, 256);
                fb.v = ldfrag(L + S1SO, sB, ko, 256);
                U8 bA, bB;
#pragma unroll
                for (int jj = 0; jj < 4; ++jj) {
                    float r0 = loF(fr.u[jj]), r1 = hiF(fr.u[jj]);
                    bA.u[jj] = pku(fmaxf(r0 + loF(fa.u[jj]), 0.f), fmaxf(r1 + hiF(fa.u[jj]), 0.f));
                    bB.u[jj] = pku(fmaxf(r0 + loF(fb.u[jj]), 0.f), fmaxf(r1 + hiF(fb.u[jj]), 0.f));
                }
#pragma unroll
                for (int m = 0; m < 8; ++m) {
                    bf16x8 Af = ldfrag(L + BIGO, m * 16 + lx, ko, 256);
                    acc2[m][0] = MFMA(Af, bA.v, acc2[m][0]);
                    acc2[m][1] = MFMA(Af, bB.v, acc2[m][1]);
                }
            }
            // ---- epilogue: fr3 GEMM through [16][40] quarters, h-outer so each
            // bW[4] load serves both cc halves
            f32x4 acc3[2][4];
#pragma unroll
            for (int cc = 0; cc < 2; ++cc)
#pragma unroll
                for (int n3 = 0; n3 < 4; ++n3) acc3[cc][n3] = (f32x4){0.f,0.f,0.f,0.f};
#pragma unroll
            for (int h = 0; h < 4; ++h) {
                bf16x8 bW[4];
#pragma unroll
                for (int n3 = 0; n3 < 4; ++n3)
                    bW[n3] = ldfrag(L + F3LO, n3 * 16 + lx, h * 32 + lq * 8, 128);
#pragma unroll
                for (int cc = 0; cc < 2; ++cc) {
                    stAct040(a2w, lx, lq * 4,      acc2[2 * h][cc]);
                    stAct040(a2w, lx, 16 + lq * 4, acc2[2 * h + 1][cc]);
                    bf16x8 af = ldfrag40(a2w, lx, lq * 8);
#pragma unroll
                    for (int n3 = 0; n3 < 4; ++n3)
                        acc3[cc][n3] = MFMA(af, bW[n3], acc3[cc][n3]);
                }
            }
#pragma unroll
            for (int cc = 0; cc < 2; ++cc) {
                bool mpad = (p == 1) && (cc == 1) && (lq == 3);
#pragma unroll
                for (int n3 = 0; n3 < 4; ++n3) {
                    float bv = b3c[n3];
                    float s = fmaxf(acc3[cc][n3][0] + bv, 0.f) + fmaxf(acc3[cc][n3][1] + bv, 0.f)
                            + fmaxf(acc3[cc][n3][2] + bv, 0.f);
                    float s3 = fmaxf(acc3[cc][n3][3] + bv, 0.f);
                    part[n3] += s + (mpad ? 0.f : s3);
                }
            }
        }
#pragma unroll
        for (int n3 = 0; n3 < 4; ++n3) {
            part[n3] += __shfl_xor(part[n3], 16, 64);
            part[n3] += __shfl_xor(part[n3], 32, 64);
        }
        if (lq == 0) {
#pragma unroll
            for (int n3 = 0; n3 < 4; ++n3)
                L[S1RO + sidx(r, n3 * 16 + lx, 256)] = f2b(part[n3]);
        }
    }
    __syncthreads();

    // ================= phase N =================
    // fo1 -> BIG, xnT -> XNTP region (a2w dead) : pure copies
    wcopy(L + BIGO, wsw + W_FO1, 32768, t);
    wcopy(L + XNTP, wsw + W_XNT + (b << 12), 4096, t);
    __syncthreads();

    // L1N: M=256 (16 m-tiles over 12 waves), N=64 nodes, K=128
    // (ks 0,1 ebar from S1RO cols 0..63; ks 2,3 xn from XNTP)
    for (int mt = w; mt < 16; mt += 12) {
        f32x4 accN[4];
#pragma unroll
        for (int nt = 0; nt < 4; ++nt) accN[nt] = (f32x4){0.f,0.f,0.f,0.f};
#pragma unroll
        for (int ks = 0; ks < 4; ++ks) {
            bf16x8 Af = ldfrag(L + BIGO, mt * 16 + lx, ks * 32 + lq * 8, 128);
#pragma unroll
            for (int nt = 0; nt < 4; ++nt) {
                bf16x8 Bf = (ks < 2) ? ldfrag(L + S1RO, nt * 16 + lx, ks * 32 + lq * 8, 256)
                                     : ldfrag(L + XNTP, nt * 16 + lx, (ks - 2) * 32 + lq * 8, 64);
                accN[nt] = MFMA(Af, Bf, accN[nt]);
            }
        }
        int ch0 = mt * 16 + lq * 4;
        float4 bi = *(const float4*)(fo1_b + ch0);
#pragma unroll
        for (int nt = 0; nt < 4; ++nt)
            stAct(L + S1SO, nt * 16 + lx, ch0, 256, accN[nt], bi);
    }
    __syncthreads();   // BIG/S1RO/XNTP reads done

    // fo2 -> BIG, fo3 -> S1RO (pure copies)
    wcopy(L + BIGO, wsw + W_FO2, 32768, t);
    wcopy(L + S1RO, wsw + W_FO3, 8192, t);
    __syncthreads();

    // L2N: M=128 (waves 0..7), N=64, K=256 -> act2N @ F3LO [64][128]
    if (w < 8) {
        f32x4 a2N[4];
#pragma unroll
        for (int nt = 0; nt < 4; ++nt) a2N[nt] = (f32x4){0.f,0.f,0.f,0.f};
#pragma unroll
        for (int ks = 0; ks < 8; ++ks) {
            bf16x8 Af = ldfrag(L + BIGO, w * 16 + lx, ks * 32 + lq * 8, 256);
#pragma unroll
            for (int nt = 0; nt < 4; ++nt) {
                bf16x8 Bf = ldfrag(L + S1SO, nt * 16 + lx, ks * 32 + lq * 8, 256);
                a2N[nt] = MFMA(Af, Bf, a2N[nt]);
            }
        }
        int ch0 = w * 16 + lq * 4;
        float4 bi = *(const float4*)(fo2_b + ch0);
#pragma unroll
        for (int nt = 0; nt < 4; ++nt)
            stAct(L + F3LO, nt * 16 + lx, ch0, 128, a2N[nt], bi);
    }
    __syncthreads();

    // L3N: M=64 (fo3 ch), N=64 nodes, K=128 (waves 0..3); relu+bias, sum over nodes
    if (w < 4) {
        f32x4 a3N[4];
#pragma unroll
        for (int nt = 0; nt < 4; ++nt) a3N[nt] = (f32x4){0.f,0.f,0.f,0.f};
#pragma unroll
        for (int ks3 = 0; ks3 < 4; ++ks3) {
            bf16x8 Af = ldfrag(L + S1RO, 16 * w + lx, ks3 * 32 + lq * 8, 128);
#pragma unroll
            for (int nt = 0; nt < 4; ++nt) {
                bf16x8 Bf = ldfrag(L + F3LO, nt * 16 + lx, ks3 * 32 + lq * 8, 128);
                a3N[nt] = MFMA(Af, Bf, a3N[nt]);
            }
        }
        float4 b3 = *(const float4*)(fo3_b + 16 * w + lq * 4);
        float o0 = 0.f, o1 = 0.f, o2 = 0.f, o3 = 0.f;
#pragma unroll
        for (int nt = 0; nt < 4; ++nt) {
            o0 += fmaxf(a3N[nt][0] + b3.x, 0.f);
            o1 += fmaxf(a3N[nt][1] + b3.y, 0.f);
            o2 += fmaxf(a3N[nt][2] + b3.z, 0.f);
            o3 += fmaxf(a3N[nt][3] + b3.w, 0.f);
        }
#pragma unroll
        for (int off = 8; off >= 1; off >>= 1) {
            o0 += __shfl_xor(o0, off, 16);
            o1 += __shfl_xor(o1, off, 16);
            o2 += __shfl_xor(o2, off, 16);
            o3 += __shfl_xor(o3, off, 16);
        }
        if (lx == 0) {
            float* red = (float*)(L + REDO);
            *(float4*)&red[16 * w + lq * 4] = make_float4(o0, o1, o2, o3);
        }
    }
    __syncthreads();

    // ---- final FCs (fp32), wave-parallel: one 64-lane dot + reduce per output
    {
        float* red = (float*)(L + REDO);
        float* h1  = red + 64;
        float* h2  = red + 96;
        for (int o = w; o < 25; o += 12) {            // fc1: 25 out, k=64
            float v = fc1_w[o * 64 + l] * red[l];
#pragma unroll
            for (int off = 32; off >= 1; off >>= 1) v += __shfl_xor(v, off, 64);
            if (l == 0) h1[o] = v + fc1_b[o];
        }
        __syncthreads();
        for (int o = w; o < 15; o += 12) {            // fc2: 15 out, k=25
            float v = (l < 25) ? fc2_w[o * 25 + l] * h1[l] : 0.f;
#pragma unroll
            for (int off = 32; off >= 1; off >>= 1) v += __shfl_xor(v, off, 64);
            if (l == 0) h2[o] = v + fc2_b[o];
        }
        __syncthreads();
        if (w < 5) {                                   // fc3: 5 out, k=15
            float v = (l < 15) ? fc3_w[w * 15 + l] * h2[l] : 0.f;
#pragma unroll
            for (int off = 32; off >= 1; off >>= 1) v += __shfl_xor(v, off, 64);
            if (l == 0) out[b * 5 + w] = v + fc3_b[w];
        }
    }
}

extern "C" void kernel_launch(void* const* d_in, const int* in_sizes, int n_in,
                              void* d_out, int out_size, void* d_ws, size_t ws_size,
                              hipStream_t stream)
{
    const float* x        = (const float*)d_in[0];
    const float* bn_gamma = (const float*)d_in[3];
    const float* bn_beta  = (const float*)d_in[4];
    const float* fr1_w = (const float*)d_in[5];
    const float* fr1_b = (const float*)d_in[6];
    const float* fr2_w = (const float*)d_in[7];
    const float* fr2_b = (const float*)d_in[8];
    const float* fr3_w = (const float*)d_in[9];
    const float* fr3_b = (const float*)d_in[10];
    const float* fo1_w = (const float*)d_in[11];
    const float* fo1_b = (const float*)d_in[12];
    const float* fo2_w = (const float*)d_in[13];
    const float* fo2_b = (const float*)d_in[14];
    const float* fo3_w = (const float*)d_in[15];
    const float* fo3_b = (const float*)d_in[16];
    const float* fc1_w = (const float*)d_in[17];
    const float* fc1_b = (const float*)d_in[18];
    const float* fc2_w = (const float*)d_in[19];
    const float* fc2_b = (const float*)d_in[20];
    const float* fc3_w = (const float*)d_in[21];
    const float* fc3_b = (const float*)d_in[22];

    float* ws    = (float*)d_ws;
    float* scale = ws;
    float* bias  = ws + 64;
    ushort* wsw  = (ushort*)(ws + 128);   // W_ALL ushorts ~ 2.4 MB (weights + xnT)
    float* out   = (float*)d_out;

    bn_stats_kernel<<<dim3(PP), dim3(1024), 0, stream>>>(x, bn_gamma, bn_beta, scale, bias);
    prep_kernel<<<dim3(W_ALL / 512), dim3(512), 0, stream>>>(
        fr1_w, fr2_w, fr3_w, fo1_w, fo2_w, fo3_w, x, scale, bias, wsw);
    meg_kernel<<<dim3(BB), dim3(768), 0, stream>>>(
        wsw,
        fr1_b, fr2_b, fr3_b, fo1_b, fo2_b, fo3_b,
        fc1_w, fc1_b, fc2_w, fc2_b, fc3_w, fc3_b, out);
}

// Round 16
// 206.799 us; speedup vs baseline: 1.3499x; 1.0891x over previous
//
#include <hip/hip_runtime.h>
#include <hip/hip_fp16.h>

#define BB 256
#define PP 48
#define NN 64
#define EPSBN 1e-5f

typedef __attribute__((ext_vector_type(8))) short sh8;      // 8 x f16 bits
typedef __attribute__((ext_vector_type(8))) _Float16 f16x8;
typedef __attribute__((ext_vector_type(4))) float f32x4;
typedef __attribute__((ext_vector_type(2))) _Float16 f16x2;
typedef __attribute__((ext_vector_type(2))) __fp16 fp16v2;  // cvt_pkrtz return type

// ---- LDS regions (ushort offsets), total 81920 ushorts = 163840 B (160 KiB) ----
#define BIGO 0       // 32768: fr1R/[+16384]fr1S -> fr2 [128][256]   | N: fo1 [256][128] -> fo2 [128][256]
#define S1SO 32768   // 16384: S1S [64][256]                          | N: act1N [64][256]
#define S1RO 49152   // 16384: S1R [64][256]; cols 0..63 ebar         | N: fo3 [64][128]
#define F3LO 65536   //  8192: fr3 [64][128] (phase E B-operand)      | N: act2N [64][128]
#define A2WO 73728   //  7680: phase E: 12 waves x 640 ([16][40] stride-40)
#define XNTP 73728   //  4096: xnT [64][64] (prologue GEMM1 + phase-N L1N; clobbered by a2w in phase E)
#define B2LO 81408   //   256: fr2_b as 128 floats (phase E only)
#define REDO 81664   //   256: phase-N-end red/h1/h2 floats
#define LDSE 81920

// ---- ws regions (ushort offsets into wsw = ws + 128 floats) ----
#define W_FR1R 0        // 16384: [256][64]
#define W_FR1S 16384    // 16384: [256][64]
#define W_FR2  32768    // 32768: [128][256]
#define W_FR3  65536    //  8192: [64][128]
#define W_FO1  73728    // 32768: [256][128]
#define W_FO2  106496   // 32768: [128][256]
#define W_FO3  139264   //  8192: [64][128]
#define W_TOT  147456
#define W_XNT  147456   // 256 x 4096: per-batch xnT [64][64]-swizzled f16
#define W_ALL  (W_XNT + BB * 4096)

union U8 { sh8 v; unsigned u[4]; };
union H2U { unsigned u; f16x2 f; fp16v2 p; };

// pack two f32 -> two f16 in one instr (v_cvt_pkrtz_f16_f32)
__device__ __forceinline__ unsigned pkh(float a, float b) {
    H2U c; c.p = __builtin_amdgcn_cvt_pkrtz(a, b);
    return c.u;
}
__device__ __forceinline__ ushort f2h(float f) {
    union { _Float16 h; ushort s; } c; c.h = (_Float16)f;
    return c.s;
}
// packed f16 relu(a+b): vector add lowers to v_pk_add_f16,
// elementwise_max lowers to v_pk_max_f16 (no HIP half2 overloads involved).
__device__ __forceinline__ unsigned reluAddH2(unsigned a, unsigned b) {
    H2U x, y, r;
    x.u = a; y.u = b;
    f16x2 s = x.f + y.f;
    f16x2 z = {(_Float16)0.f, (_Float16)0.f};
    r.f = __builtin_elementwise_max(s, z);
    return r.u;
}

__device__ __forceinline__ int sidx(int row, int k, int kpad) {
    return row * kpad + ((((k >> 3) ^ (row & 7)) << 3) | (k & 7));
}
__device__ __forceinline__ sh8 ldfrag(const ushort* buf, int row, int k, int kpad) {
    return *(const sh8*)(buf + row * kpad + (((k >> 3) ^ (row & 7)) << 3));
}
// [16][40] wave-private buffer: 80 B row stride spreads rows over banks (~2-way)
__device__ __forceinline__ sh8 ldfrag40(const ushort* buf, int row, int k) {
    return *(const sh8*)(buf + row * 40 + k);
}
__device__ __forceinline__ f32x4 MFMA(sh8 a, sh8 b, f32x4 c) {
    union { sh8 s; f16x8 f; } ca, cb;
    ca.s = a; cb.s = b;
    return __builtin_amdgcn_mfma_f32_16x16x32_f16(ca.f, cb.f, c, 0, 0, 0);
}
__device__ __forceinline__ void stAct(ushort* buf, int row, int c0, int kpad, f32x4 a, float4 bi) {
    uint2 o;
    o.x = pkh(fmaxf(a[0] + bi.x, 0.f), fmaxf(a[1] + bi.y, 0.f));
    o.y = pkh(fmaxf(a[2] + bi.z, 0.f), fmaxf(a[3] + bi.w, 0.f));
    *(uint2*)(buf + row * kpad + ((((c0 >> 3) ^ (row & 7)) << 3) | (c0 & 7))) = o;
}
// bias folded into accumulator init: store relu(acc); stride-40 variant
__device__ __forceinline__ void stAct040(ushort* buf, int row, int c0, f32x4 a) {
    uint2 o;
    o.x = pkh(fmaxf(a[0], 0.f), fmaxf(a[1], 0.f));
    o.y = pkh(fmaxf(a[2], 0.f), fmaxf(a[3], 0.f));
    *(uint2*)(buf + row * 40 + c0) = o;
}
__device__ __forceinline__ void stRaw(ushort* buf, int row, int c0, int kpad, f32x4 a, float4 bi) {
    uint2 o;
    o.x = pkh(a[0] + bi.x, a[1] + bi.y);
    o.y = pkh(a[2] + bi.z, a[3] + bi.w);
    *(uint2*)(buf + row * kpad + ((((c0 >> 3) ^ (row & 7)) << 3) | (c0 & 7))) = o;
}

// ---------------- batchnorm stats (1024 threads) ----------------
__global__ __launch_bounds__(1024) void bn_stats_kernel(
    const float* __restrict__ x, const float* __restrict__ gamma,
    const float* __restrict__ beta, float* __restrict__ scale, float* __restrict__ bias)
{
    __shared__ float s_sum[1024], s_sq[1024];
    int p = blockIdx.x, t = threadIdx.x;
    float sum = 0.f, sq = 0.f;
    for (int i = t; i < BB * NN; i += 1024) {
        int b = i >> 6, n = i & 63;
        float v = x[b * PP * NN + p * NN + n];
        sum += v; sq += v * v;
    }
    s_sum[t] = sum; s_sq[t] = sq;
    __syncthreads();
    for (int off = 512; off > 0; off >>= 1) {
        if (t < off) { s_sum[t] += s_sum[t + off]; s_sq[t] += s_sq[t + off]; }
        __syncthreads();
    }
    if (t == 0) {
        float inv = 1.f / (float)(BB * NN);
        float mean = s_sum[0] * inv;
        float var  = s_sq[0] * inv - mean * mean;
        float sc   = gamma[p] * rsqrtf(var + EPSBN);
        scale[p] = sc;
        bias[p]  = beta[p] - mean * sc;
    }
}

// ---------------- prep: weights f32->f16 pre-swizzled + per-batch xnT ----------------
__global__ __launch_bounds__(512) void prep_kernel(
    const float* __restrict__ fr1_w, const float* __restrict__ fr2_w,
    const float* __restrict__ fr3_w, const float* __restrict__ fo1_w,
    const float* __restrict__ fo2_w, const float* __restrict__ fo3_w,
    const float* __restrict__ x, const float* __restrict__ scale,
    const float* __restrict__ bias, ushort* __restrict__ wsw)
{
    int i = blockIdx.x * 512 + threadIdx.x;
    if (i >= W_ALL) return;
    if (i >= W_TOT) {
        int j = i - W_XNT;
        int b = j >> 12, nk = j & 4095, n = nk & 63, k = nk >> 6;
        float v = (k < PP) ? x[b * PP * NN + k * NN + n] * scale[k] + bias[k] : 0.f;
        wsw[W_XNT + (b << 12) + sidx(n, k, 64)] = f2h(v);
        return;
    }
    float v; int off, row, k, kpad;
    if (i < 16384)        { row = i >> 6; k = i & 63; kpad = 64;  off = W_FR1R;
                            v = (k < PP) ? fr1_w[row * 96 + k] : 0.f; }
    else if (i < 32768)   { int j = i - 16384;  row = j >> 6; k = j & 63;  kpad = 64;  off = W_FR1S;
                            v = (k < PP) ? fr1_w[row * 96 + PP + k] : 0.f; }
    else if (i < 65536)   { int j = i - 32768;  row = j >> 8; k = j & 255; kpad = 256; off = W_FR2;
                            v = fr2_w[row * 256 + k]; }
    else if (i < 73728)   { int j = i - 65536;  row = j >> 7; k = j & 127; kpad = 128; off = W_FR3;
                            v = fr3_w[row * 128 + k]; }
    else if (i < 106496)  { int j = i - 73728;  row = j >> 7; k = j & 127; kpad = 128; off = W_FO1;
                            v = (k < 64) ? fo1_w[row * 112 + PP + k]
                              : (k < 112 ? fo1_w[row * 112 + (k - 64)] : 0.f); }
    else if (i < 139264)  { int j = i - 106496; row = j >> 8; k = j & 255; kpad = 256; off = W_FO2;
                            v = fo2_w[row * 256 + k]; }
    else                  { int j = i - 139264; row = j >> 7; k = j & 127; kpad = 128; off = W_FO3;
                            v = fo3_w[row * 128 + k]; }
    wsw[off + sidx(row, k, kpad)] = f2h(v);
}

// copy n ushorts (layout-identical) ws -> LDS, uint4-vectorized, 768 threads
__device__ __forceinline__ void wcopy(ushort* dst, const ushort* src, int n, int t) {
    for (int i = t * 8; i < n; i += 768 * 8)
        *(uint4*)(dst + i) = *(const uint4*)(src + i);
}

// ---------------- mega kernel: one block per batch, 12 waves (3/SIMD) ----------------
// R15 = R13/R14 design (f16 internal precision, native v_pk_add_f16 /
// v_pk_max_f16 edge-build) with the cvt_pkrtz return type fixed (__fp16 vec2).
__global__ __launch_bounds__(768, 3) void meg_kernel(
    const ushort* __restrict__ wsw,
    const float* __restrict__ fr1_b, const float* __restrict__ fr2_b,
    const float* __restrict__ fr3_b, const float* __restrict__ fo1_b,
    const float* __restrict__ fo2_b, const float* __restrict__ fo3_b,
    const float* __restrict__ fc1_w, const float* __restrict__ fc1_b,
    const float* __restrict__ fc2_w, const float* __restrict__ fc2_b,
    const float* __restrict__ fc3_w, const float* __restrict__ fc3_b,
    float* __restrict__ out)
{
    __shared__ __align__(16) ushort L[LDSE];

    int b = blockIdx.x, t = threadIdx.x;
    int w = t >> 6, l = t & 63, lx = l & 15, lq = l >> 4;

    // ---- prologue staging: pure copies from pre-swizzled ws
    wcopy(L + XNTP,         wsw + W_XNT + (b << 12), 4096, t);
    wcopy(L + BIGO,         wsw + W_FR1R, 16384, t);
    wcopy(L + BIGO + 16384, wsw + W_FR1S, 16384, t);
    wcopy(L + F3LO,         wsw + W_FR3,  8192, t);
    if (t < 128) ((float*)(L + B2LO))[t] = fr2_b[t];
    __syncthreads();

    // ---- GEMM1+2 fused: S1R = fr1R.xn + b1, S1S = fr1S.xn (16 m-tiles over 12 waves)
    for (int mt = w; mt < 16; mt += 12) {
        f32x4 aR[4], aS[4];
#pragma unroll
        for (int nt = 0; nt < 4; ++nt) { aR[nt] = (f32x4){0.f,0.f,0.f,0.f}; aS[nt] = (f32x4){0.f,0.f,0.f,0.f}; }
#pragma unroll
        for (int ks = 0; ks < 2; ++ks) {
            sh8 AfR = ldfrag(L + BIGO,         mt * 16 + lx, ks * 32 + lq * 8, 64);
            sh8 AfS = ldfrag(L + BIGO + 16384, mt * 16 + lx, ks * 32 + lq * 8, 64);
#pragma unroll
            for (int nt = 0; nt < 4; ++nt) {
                sh8 Bf = ldfrag(L + XNTP, nt * 16 + lx, ks * 32 + lq * 8, 64);
                aR[nt] = MFMA(AfR, Bf, aR[nt]);
                aS[nt] = MFMA(AfS, Bf, aS[nt]);
            }
        }
        int ch0 = mt * 16 + lq * 4;
        float4 bi = *(const float4*)(fr1_b + ch0);
        float4 zb = make_float4(0.f, 0.f, 0.f, 0.f);
#pragma unroll
        for (int nt = 0; nt < 4; ++nt) {
            stRaw(L + S1RO, nt * 16 + lx, ch0, 256, aR[nt], bi);
            stRaw(L + S1SO, nt * 16 + lx, ch0, 256, aS[nt], zb);
        }
    }
    __syncthreads();   // BIG/XNTP reads done; restage fr2 below

    // ---- fr2 -> BIG (pure copy)
    wcopy(L + BIGO, wsw + W_FR2, 32768, t);
    float b3c[4];
#pragma unroll
    for (int n3 = 0; n3 < 4; ++n3) b3c[n3] = fr3_b[n3 * 16 + lx];
    __syncthreads();

    // ================= phase E: receivers strided over 12 waves, zero barriers =================
    ushort* a2w = L + A2WO + w * 640;     // wave-private [16][40]
    const float* b2L = (const float*)(L + B2LO);
#pragma unroll 1
    for (int r = w; r < 64; r += 12) {
        float part[4] = {0.f, 0.f, 0.f, 0.f};
#pragma unroll 1
        for (int p = 0; p < 2; ++p) {
            int eA = p * 32 + lx, eB = eA + 16;
            int sA = eA + (eA >= r);
            int sB = eB + (eB >= r); if (sB > 63) sB = 63;   // pad edge 63

            f32x4 acc2[8][2];
#pragma unroll
            for (int m = 0; m < 8; ++m) {
                float4 bv = *(const float4*)(b2L + m * 16 + lq * 4);
                f32x4 bi; bi[0] = bv.x; bi[1] = bv.y; bi[2] = bv.z; bi[3] = bv.w;
                acc2[m][0] = bi; acc2[m][1] = bi;
            }
#pragma unroll
            for (int ks = 0; ks < 8; ++ks) {
                int ko = ks * 32 + lq * 8;
                U8 fr, fa, fb;
                fr.v = ldfrag(L + S1RO, r,  ko, 256);   // wave-uniform row: broadcast
                fa.v = ldfrag(L + S1SO, sA, ko, 256);
                fb.v = ldfrag(L + S1SO, sB, ko, 256);
                U8 bA, bB;
#pragma unroll
                for (int jj = 0; jj < 4; ++jj) {
                    bA.u[jj] = reluAddH2(fr.u[jj], fa.u[jj]);   // v_pk_add_f16 + v_pk_max_f16
                    bB.u[jj] = reluAddH2(fr.u[jj], fb.u[jj]);
                }
#pragma unroll
                for (int m = 0; m < 8; ++m) {
                    sh8 Af = ldfrag(L + BIGO, m * 16 + lx, ko, 256);
                    acc2[m][0] = MFMA(Af, bA.v, acc2[m][0]);
                    acc2[m][1] = MFMA(Af, bB.v, acc2[m][1]);
                }
            }
            // ---- epilogue: fr3 GEMM through [16][40] quarters, h-outer so each
            // bW[4] load serves both cc halves
            f32x4 acc3[2][4];
#pragma unroll
            for (int cc = 0; cc < 2; ++cc)
#pragma unroll
                for (int n3 = 0; n3 < 4; ++n3) acc3[cc][n3] = (f32x4){0.f,0.f,0.f,0.f};
#pragma unroll
            for (int h = 0; h < 4; ++h) {
                sh8 bW[4];
#pragma unroll
                for (int n3 = 0; n3 < 4; ++n3)
                    bW[n3] = ldfrag(L + F3LO, n3 * 16 + lx, h * 32 + lq * 8, 128);
#pragma unroll
                for (int cc = 0; cc < 2; ++cc) {
                    stAct040(a2w, lx, lq * 4,      acc2[2 * h][cc]);
                    stAct040(a2w, lx, 16 + lq * 4, acc2[2 * h + 1][cc]);
                    sh8 af = ldfrag40(a2w, lx, lq * 8);
#pragma unroll
                    for (int n3 = 0; n3 < 4; ++n3)
                        acc3[cc][n3] = MFMA(af, bW[n3], acc3[cc][n3]);
                }
            }
#pragma unroll
            for (int cc = 0; cc < 2; ++cc) {
                bool mpad = (p == 1) && (cc == 1) && (lq == 3);
#pragma unroll
                for (int n3 = 0; n3 < 4; ++n3) {
                    float bv = b3c[n3];
                    float s = fmaxf(acc3[cc][n3][0] + bv, 0.f) + fmaxf(acc3[cc][n3][1] + bv, 0.f)
                            + fmaxf(acc3[cc][n3][2] + bv, 0.f);
                    float s3 = fmaxf(acc3[cc][n3][3] + bv, 0.f);
                    part[n3] += s + (mpad ? 0.f : s3);
                }
            }
        }
#pragma unroll
        for (int n3 = 0; n3 < 4; ++n3) {
            part[n3] += __shfl_xor(part[n3], 16, 64);
            part[n3] += __shfl_xor(part[n3], 32, 64);
        }
        if (lq == 0) {
#pragma unroll
            for (int n3 = 0; n3 < 4; ++n3)
                L[S1RO + sidx(r, n3 * 16 + lx, 256)] = f2h(part[n3]);
        }
    }
    __syncthreads();

    // ================= phase N =================
    // fo1 -> BIG, xnT -> XNTP region (a2w dead) : pure copies
    wcopy(L + BIGO, wsw + W_FO1, 32768, t);
    wcopy(L + XNTP, wsw + W_XNT + (b << 12), 4096, t);
    __syncthreads();

    // L1N: M=256 (16 m-tiles over 12 waves), N=64 nodes, K=128
    // (ks 0,1 ebar from S1RO cols 0..63; ks 2,3 xn from XNTP)
    for (int mt = w; mt < 16; mt += 12) {
        f32x4 accN[4];
#pragma unroll
        for (int nt = 0; nt < 4; ++nt) accN[nt] = (f32x4){0.f,0.f,0.f,0.f};
#pragma unroll
        for (int ks = 0; ks < 4; ++ks) {
            sh8 Af = ldfrag(L + BIGO, mt * 16 + lx, ks * 32 + lq * 8, 128);
#pragma unroll
            for (int nt = 0; nt < 4; ++nt) {
                sh8 Bf = (ks < 2) ? ldfrag(L + S1RO, nt * 16 + lx, ks * 32 + lq * 8, 256)
                                  : ldfrag(L + XNTP, nt * 16 + lx, (ks - 2) * 32 + lq * 8, 64);
                accN[nt] = MFMA(Af, Bf, accN[nt]);
            }
        }
        int ch0 = mt * 16 + lq * 4;
        float4 bi = *(const float4*)(fo1_b + ch0);
#pragma unroll
        for (int nt = 0; nt < 4; ++nt)
            stAct(L + S1SO, nt * 16 + lx, ch0, 256, accN[nt], bi);
    }
    __syncthreads();   // BIG/S1RO/XNTP reads done

    // fo2 -> BIG, fo3 -> S1RO (pure copies)
    wcopy(L + BIGO, wsw + W_FO2, 32768, t);
    wcopy(L + S1RO, wsw + W_FO3, 8192, t);
    __syncthreads();

    // L2N: M=128 (waves 0..7), N=64, K=256 -> act2N @ F3LO [64][128]
    if (w < 8) {
        f32x4 a2N[4];
#pragma unroll
        for (int nt = 0; nt < 4; ++nt) a2N[nt] = (f32x4){0.f,0.f,0.f,0.f};
#pragma unroll
        for (int ks = 0; ks < 8; ++ks) {
            sh8 Af = ldfrag(L + BIGO, w * 16 + lx, ks * 32 + lq * 8, 256);
#pragma unroll
            for (int nt = 0; nt < 4; ++nt) {
                sh8 Bf = ldfrag(L + S1SO, nt * 16 + lx, ks * 32 + lq * 8, 256);
                a2N[nt] = MFMA(Af, Bf, a2N[nt]);
            }
        }
        int ch0 = w * 16 + lq * 4;
        float4 bi = *(const float4*)(fo2_b + ch0);
#pragma unroll
        for (int nt = 0; nt < 4; ++nt)
            stAct(L + F3LO, nt * 16 + lx, ch0, 128, a2N[nt], bi);
    }
    __syncthreads();

    // L3N: M=64 (fo3 ch), N=64 nodes, K=128 (waves 0..3); relu+bias, sum over nodes
    if (w < 4) {
        f32x4 a3N[4];
#pragma unroll
        for (int nt = 0; nt < 4; ++nt) a3N[nt] = (f32x4){0.f,0.f,0.f,0.f};
#pragma unroll
        for (int ks3 = 0; ks3 < 4; ++ks3) {
            sh8 Af = ldfrag(L + S1RO, 16 * w + lx, ks3 * 32 + lq * 8, 128);
#pragma unroll
            for (int nt = 0; nt < 4; ++nt) {
                sh8 Bf = ldfrag(L + F3LO, nt * 16 + lx, ks3 * 32 + lq * 8, 128);
                a3N[nt] = MFMA(Af, Bf, a3N[nt]);
            }
        }
        float4 b3 = *(const float4*)(fo3_b + 16 * w + lq * 4);
        float o0 = 0.f, o1 = 0.f, o2 = 0.f, o3 = 0.f;
#pragma unroll
        for (int nt = 0; nt < 4; ++nt) {
            o0 += fmaxf(a3N[nt][0] + b3.x, 0.f);
            o1 += fmaxf(a3N[nt][1] + b3.y, 0.f);
            o2 += fmaxf(a3N[nt][2] + b3.z, 0.f);
            o3 += fmaxf(a3N[nt][3] + b3.w, 0.f);
        }
#pragma unroll
        for (int off = 8; off >= 1; off >>= 1) {
            o0 += __shfl_xor(o0, off, 16);
            o1 += __shfl_xor(o1, off, 16);
            o2 += __shfl_xor(o2, off, 16);
            o3 += __shfl_xor(o3, off, 16);
        }
        if (lx == 0) {
            float* red = (float*)(L + REDO);
            *(float4*)&red[16 * w + lq * 4] = make_float4(o0, o1, o2, o3);
        }
    }
    __syncthreads();

    // ---- final FCs (fp32), wave-parallel: one 64-lane dot + reduce per output
    {
        float* red = (float*)(L + REDO);
        float* h1  = red + 64;
        float* h2  = red + 96;
        for (int o = w; o < 25; o += 12) {            // fc1: 25 out, k=64
            float v = fc1_w[o * 64 + l] * red[l];
#pragma unroll
            for (int off = 32; off >= 1; off >>= 1) v += __shfl_xor(v, off, 64);
            if (l == 0) h1[o] = v + fc1_b[o];
        }
        __syncthreads();
        for (int o = w; o < 15; o += 12) {            // fc2: 15 out, k=25
            float v = (l < 25) ? fc2_w[o * 25 + l] * h1[l] : 0.f;
#pragma unroll
            for (int off = 32; off >= 1; off >>= 1) v += __shfl_xor(v, off, 64);
            if (l == 0) h2[o] = v + fc2_b[o];
        }
        __syncthreads();
        if (w < 5) {                                   // fc3: 5 out, k=15
            float v = (l < 15) ? fc3_w[w * 15 + l] * h2[l] : 0.f;
#pragma unroll
            for (int off = 32; off >= 1; off >>= 1) v += __shfl_xor(v, off, 64);
            if (l == 0) out[b * 5 + w] = v + fc3_b[w];
        }
    }
}

extern "C" void kernel_launch(void* const* d_in, const int* in_sizes, int n_in,
                              void* d_out, int out_size, void* d_ws, size_t ws_size,
                              hipStream_t stream)
{
    const float* x        = (const float*)d_in[0];
    const float* bn_gamma = (const float*)d_in[3];
    const float* bn_beta  = (const float*)d_in[4];
    const float* fr1_w = (const float*)d_in[5];
    const float* fr1_b = (const float*)d_in[6];
    const float* fr2_w = (const float*)d_in[7];
    const float* fr2_b = (const float*)d_in[8];
    const float* fr3_w = (const float*)d_in[9];
    const float* fr3_b = (const float*)d_in[10];
    const float* fo1_w = (const float*)d_in[11];
    const float* fo1_b = (const float*)d_in[12];
    const float* fo2_w = (const float*)d_in[13];
    const float* fo2_b = (const float*)d_in[14];
    const float* fo3_w = (const float*)d_in[15];
    const float* fo3_b = (const float*)d_in[16];
    const float* fc1_w = (const float*)d_in[17];
    const float* fc1_b = (const float*)d_in[18];
    const float* fc2_w = (const float*)d_in[19];
    const float* fc2_b = (const float*)d_in[20];
    const float* fc3_w = (const float*)d_in[21];
    const float* fc3_b = (const float*)d_in[22];

    float* ws    = (float*)d_ws;
    float* scale = ws;
    float* bias  = ws + 64;
    ushort* wsw  = (ushort*)(ws + 128);   // W_ALL ushorts ~ 2.4 MB (weights + xnT)
    float* out   = (float*)d_out;

    bn_stats_kernel<<<dim3(PP), dim3(1024), 0, stream>>>(x, bn_gamma, bn_beta, scale, bias);
    prep_kernel<<<dim3(W_ALL / 512), dim3(512), 0, stream>>>(
        fr1_w, fr2_w, fr3_w, fo1_w, fo2_w, fo3_w, x, scale, bias, wsw);
    meg_kernel<<<dim3(BB), dim3(768), 0, stream>>>(
        wsw,
        fr1_b, fr2_b, fr3_b, fo1_b, fo2_b, fo3_b,
        fc1_w, fc1_b, fc2_w, fc2_b, fc3_w, fc3_b, out);
}

// Round 17
// 203.485 us; speedup vs baseline: 1.3719x; 1.0163x over previous
//
#include <hip/hip_runtime.h>
#include <hip/hip_fp16.h>

#define BB 256
#define PP 48
#define NN 64
#define EPSBN 1e-5f

typedef __attribute__((ext_vector_type(8))) short sh8;      // 8 x f16 bits
typedef __attribute__((ext_vector_type(8))) _Float16 f16x8;
typedef __attribute__((ext_vector_type(4))) float f32x4;
typedef __attribute__((ext_vector_type(2))) _Float16 f16x2;
typedef __attribute__((ext_vector_type(2))) __fp16 fp16v2;  // cvt_pkrtz return type

// ---- LDS regions (ushort offsets), total 81920 ushorts = 163840 B (160 KiB) ----
#define BIGO 0       // 32768: fr1R/[+16384]fr1S -> fr2 [128][256]   | N: fo1 [256][128] -> fo2 [128][256]
#define S1SO 32768   // 16384: S1S [64][256]                          | N: act1N [64][256]
#define S1RO 49152   // 16384: S1R [64][256]; cols 0..63 ebar         | N: fo3 [64][128]
#define F3LO 65536   //  8192: fr3 [64][128] (phase E B-operand)      | N: act2N [64][128]
#define A2WO 73728   //  7680: phase E: 12 waves x 640 ([16][40] stride-40)
#define XNTP 73728   //  4096: xnT [64][64] (prologue GEMM1 + phase-N L1N; clobbered by a2w in phase E)
#define B2LO 81408   //   256: fr2_b as 128 floats (phase E only)
#define REDO 81664   //   256: phase-N-end red/h1/h2 floats
#define LDSE 81920

// ---- ws weight regions (ushort offsets into wsw = ws + 128 floats) ----
#define W_FR1R 0        // 16384: [256][64]
#define W_FR1S 16384    // 16384: [256][64]
#define W_FR2  32768    // 32768: [128][256]
#define W_FR3  65536    //  8192: [64][128]
#define W_FO1  73728    // 32768: [256][128]
#define W_FO2  106496   // 32768: [128][256]
#define W_FO3  139264   //  8192: [64][128]
#define W_TOT  147456   // = 144 * 1024

union U8 { sh8 v; unsigned u[4]; };
union H2U { unsigned u; f16x2 f; fp16v2 p; };

// pack two f32 -> two f16 in one instr (v_cvt_pkrtz_f16_f32)
__device__ __forceinline__ unsigned pkh(float a, float b) {
    H2U c; c.p = __builtin_amdgcn_cvt_pkrtz(a, b);
    return c.u;
}
__device__ __forceinline__ ushort f2h(float f) {
    union { _Float16 h; ushort s; } c; c.h = (_Float16)f;
    return c.s;
}
// packed f16 relu(a+b): vector add lowers to v_pk_add_f16,
// elementwise_max lowers to v_pk_max_f16.
__device__ __forceinline__ unsigned reluAddH2(unsigned a, unsigned b) {
    H2U x, y, r;
    x.u = a; y.u = b;
    f16x2 s = x.f + y.f;
    f16x2 z = {(_Float16)0.f, (_Float16)0.f};
    r.f = __builtin_elementwise_max(s, z);
    return r.u;
}

__device__ __forceinline__ int sidx(int row, int k, int kpad) {
    return row * kpad + ((((k >> 3) ^ (row & 7)) << 3) | (k & 7));
}
__device__ __forceinline__ sh8 ldfrag(const ushort* buf, int row, int k, int kpad) {
    return *(const sh8*)(buf + row * kpad + (((k >> 3) ^ (row & 7)) << 3));
}
// [16][40] wave-private buffer: 80 B row stride spreads rows over banks (~2-way)
__device__ __forceinline__ sh8 ldfrag40(const ushort* buf, int row, int k) {
    return *(const sh8*)(buf + row * 40 + k);
}
__device__ __forceinline__ f32x4 MFMA(sh8 a, sh8 b, f32x4 c) {
    union { sh8 s; f16x8 f; } ca, cb;
    ca.s = a; cb.s = b;
    return __builtin_amdgcn_mfma_f32_16x16x32_f16(ca.f, cb.f, c, 0, 0, 0);
}
__device__ __forceinline__ void stAct(ushort* buf, int row, int c0, int kpad, f32x4 a, float4 bi) {
    uint2 o;
    o.x = pkh(fmaxf(a[0] + bi.x, 0.f), fmaxf(a[1] + bi.y, 0.f));
    o.y = pkh(fmaxf(a[2] + bi.z, 0.f), fmaxf(a[3] + bi.w, 0.f));
    *(uint2*)(buf + row * kpad + ((((c0 >> 3) ^ (row & 7)) << 3) | (c0 & 7))) = o;
}
// bias folded into accumulator init: store relu(acc); stride-40 variant
__device__ __forceinline__ void stAct040(ushort* buf, int row, int c0, f32x4 a) {
    uint2 o;
    o.x = pkh(fmaxf(a[0], 0.f), fmaxf(a[1], 0.f));
    o.y = pkh(fmaxf(a[2], 0.f), fmaxf(a[3], 0.f));
    *(uint2*)(buf + row * 40 + c0) = o;
}
__device__ __forceinline__ void stRaw(ushort* buf, int row, int c0, int kpad, f32x4 a, float4 bi) {
    uint2 o;
    o.x = pkh(a[0] + bi.x, a[1] + bi.y);
    o.y = pkh(a[2] + bi.z, a[3] + bi.w);
    *(uint2*)(buf + row * kpad + ((((c0 >> 3) ^ (row & 7)) << 3) | (c0 & 7))) = o;
}

// ---------------- fused bn-stats + weight prep ----------------
// Blocks 0..47: batchnorm stats for channel p (1024 threads, 16 latency iters).
// Blocks 48..191: f32->f16 weight conversion into pre-swizzled LDS layout
// (independent of bn, so both roles share one dispatch).
__global__ __launch_bounds__(1024) void bnprep_kernel(
    const float* __restrict__ x, const float* __restrict__ gamma,
    const float* __restrict__ beta, float* __restrict__ scale, float* __restrict__ bias,
    const float* __restrict__ fr1_w, const float* __restrict__ fr2_w,
    const float* __restrict__ fr3_w, const float* __restrict__ fo1_w,
    const float* __restrict__ fo2_w, const float* __restrict__ fo3_w,
    ushort* __restrict__ wsw)
{
    __shared__ float s_sum[1024], s_sq[1024];
    int t = threadIdx.x;
    if (blockIdx.x < PP) {
        int p = blockIdx.x;
        float sum = 0.f, sq = 0.f;
        for (int i = t; i < BB * NN; i += 1024) {
            int b = i >> 6, n = i & 63;
            float v = x[b * PP * NN + p * NN + n];
            sum += v; sq += v * v;
        }
        s_sum[t] = sum; s_sq[t] = sq;
        __syncthreads();
        for (int off = 512; off > 0; off >>= 1) {
            if (t < off) { s_sum[t] += s_sum[t + off]; s_sq[t] += s_sq[t + off]; }
            __syncthreads();
        }
        if (t == 0) {
            float inv = 1.f / (float)(BB * NN);
            float mean = s_sum[0] * inv;
            float var  = s_sq[0] * inv - mean * mean;
            float sc   = gamma[p] * rsqrtf(var + EPSBN);
            scale[p] = sc;
            bias[p]  = beta[p] - mean * sc;
        }
        return;
    }
    int i = (blockIdx.x - PP) * 1024 + t;
    if (i >= W_TOT) return;
    float v; int off, row, k, kpad;
    if (i < 16384)        { row = i >> 6; k = i & 63; kpad = 64;  off = W_FR1R;
                            v = (k < PP) ? fr1_w[row * 96 + k] : 0.f; }
    else if (i < 32768)   { int j = i - 16384;  row = j >> 6; k = j & 63;  kpad = 64;  off = W_FR1S;
                            v = (k < PP) ? fr1_w[row * 96 + PP + k] : 0.f; }
    else if (i < 65536)   { int j = i - 32768;  row = j >> 8; k = j & 255; kpad = 256; off = W_FR2;
                            v = fr2_w[row * 256 + k]; }
    else if (i < 73728)   { int j = i - 65536;  row = j >> 7; k = j & 127; kpad = 128; off = W_FR3;
                            v = fr3_w[row * 128 + k]; }
    else if (i < 106496)  { int j = i - 73728;  row = j >> 7; k = j & 127; kpad = 128; off = W_FO1;
                            v = (k < 64) ? fo1_w[row * 112 + PP + k]
                              : (k < 112 ? fo1_w[row * 112 + (k - 64)] : 0.f); }
    else if (i < 139264)  { int j = i - 106496; row = j >> 8; k = j & 255; kpad = 256; off = W_FO2;
                            v = fo2_w[row * 256 + k]; }
    else                  { int j = i - 139264; row = j >> 7; k = j & 127; kpad = 128; off = W_FO3;
                            v = fo3_w[row * 128 + k]; }
    wsw[off + sidx(row, k, kpad)] = f2h(v);
}

// copy n ushorts (layout-identical) ws -> LDS, uint4-vectorized, 768 threads
__device__ __forceinline__ void wcopy(ushort* dst, const ushort* src, int n, int t) {
    for (int i = t * 8; i < n; i += 768 * 8)
        *(uint4*)(dst + i) = *(const uint4*)(src + i);
}

// ---------------- mega kernel: one block per batch, 12 waves (3/SIMD) ----------------
// R16 = R15 compute phases (f16 internal precision) with the launch path cut
// to TWO kernels: bn+weight-prep fused (independent block roles); xnT computed
// inline in meg again (coalesced x reads, ~2 us — cheaper than prep's 5 MB of
// xnT traffic + a third launch).
__global__ __launch_bounds__(768, 3) void meg_kernel(
    const float* __restrict__ x,
    const float* __restrict__ scl, const float* __restrict__ bia,
    const ushort* __restrict__ wsw,
    const float* __restrict__ fr1_b, const float* __restrict__ fr2_b,
    const float* __restrict__ fr3_b, const float* __restrict__ fo1_b,
    const float* __restrict__ fo2_b, const float* __restrict__ fo3_b,
    const float* __restrict__ fc1_w, const float* __restrict__ fc1_b,
    const float* __restrict__ fc2_w, const float* __restrict__ fc2_b,
    const float* __restrict__ fc3_w, const float* __restrict__ fc3_b,
    float* __restrict__ out)
{
    __shared__ __align__(16) ushort L[LDSE];

    int b = blockIdx.x, t = threadIdx.x;
    int w = t >> 6, l = t & 63, lx = l & 15, lq = l >> 4;

    // ---- xnT [64][64] (cols 48..63 zero); coalesced x reads (n fastest)
    for (int i = t; i < 4096; i += 768) {
        int n = i & 63, k = i >> 6;
        float v = (k < PP) ? x[b * PP * NN + k * NN + n] * scl[k] + bia[k] : 0.f;
        L[XNTP + sidx(n, k, 64)] = f2h(v);
    }
    // ---- fr1R/fr1S/fr3: pure copies from pre-swizzled ws
    wcopy(L + BIGO,         wsw + W_FR1R, 16384, t);
    wcopy(L + BIGO + 16384, wsw + W_FR1S, 16384, t);
    wcopy(L + F3LO,         wsw + W_FR3,  8192, t);
    if (t < 128) ((float*)(L + B2LO))[t] = fr2_b[t];
    __syncthreads();

    // ---- GEMM1+2 fused: S1R = fr1R.xn + b1, S1S = fr1S.xn (16 m-tiles over 12 waves)
    for (int mt = w; mt < 16; mt += 12) {
        f32x4 aR[4], aS[4];
#pragma unroll
        for (int nt = 0; nt < 4; ++nt) { aR[nt] = (f32x4){0.f,0.f,0.f,0.f}; aS[nt] = (f32x4){0.f,0.f,0.f,0.f}; }
#pragma unroll
        for (int ks = 0; ks < 2; ++ks) {
            sh8 AfR = ldfrag(L + BIGO,         mt * 16 + lx, ks * 32 + lq * 8, 64);
            sh8 AfS = ldfrag(L + BIGO + 16384, mt * 16 + lx, ks * 32 + lq * 8, 64);
#pragma unroll
            for (int nt = 0; nt < 4; ++nt) {
                sh8 Bf = ldfrag(L + XNTP, nt * 16 + lx, ks * 32 + lq * 8, 64);
                aR[nt] = MFMA(AfR, Bf, aR[nt]);
                aS[nt] = MFMA(AfS, Bf, aS[nt]);
            }
        }
        int ch0 = mt * 16 + lq * 4;
        float4 bi = *(const float4*)(fr1_b + ch0);
        float4 zb = make_float4(0.f, 0.f, 0.f, 0.f);
#pragma unroll
        for (int nt = 0; nt < 4; ++nt) {
            stRaw(L + S1RO, nt * 16 + lx, ch0, 256, aR[nt], bi);
            stRaw(L + S1SO, nt * 16 + lx, ch0, 256, aS[nt], zb);
        }
    }
    __syncthreads();   // BIG/XNTP reads done; restage fr2 below

    // ---- fr2 -> BIG (pure copy)
    wcopy(L + BIGO, wsw + W_FR2, 32768, t);
    float b3c[4];
#pragma unroll
    for (int n3 = 0; n3 < 4; ++n3) b3c[n3] = fr3_b[n3 * 16 + lx];
    __syncthreads();

    // ================= phase E: receivers strided over 12 waves, zero barriers =================
    ushort* a2w = L + A2WO + w * 640;     // wave-private [16][40]
    const float* b2L = (const float*)(L + B2LO);
#pragma unroll 1
    for (int r = w; r < 64; r += 12) {
        float part[4] = {0.f, 0.f, 0.f, 0.f};
#pragma unroll 1
        for (int p = 0; p < 2; ++p) {
            int eA = p * 32 + lx, eB = eA + 16;
            int sA = eA + (eA >= r);
            int sB = eB + (eB >= r); if (sB > 63) sB = 63;   // pad edge 63

            f32x4 acc2[8][2];
#pragma unroll
            for (int m = 0; m < 8; ++m) {
                float4 bv = *(const float4*)(b2L + m * 16 + lq * 4);
                f32x4 bi; bi[0] = bv.x; bi[1] = bv.y; bi[2] = bv.z; bi[3] = bv.w;
                acc2[m][0] = bi; acc2[m][1] = bi;
            }
#pragma unroll
            for (int ks = 0; ks < 8; ++ks) {
                int ko = ks * 32 + lq * 8;
                U8 fr, fa, fb;
                fr.v = ldfrag(L + S1RO, r,  ko, 256);   // wave-uniform row: broadcast
                fa.v = ldfrag(L + S1SO, sA, ko, 256);
                fb.v = ldfrag(L + S1SO, sB, ko, 256);
                U8 bA, bB;
#pragma unroll
                for (int jj = 0; jj < 4; ++jj) {
                    bA.u[jj] = reluAddH2(fr.u[jj], fa.u[jj]);   // v_pk_add_f16 + v_pk_max_f16
                    bB.u[jj] = reluAddH2(fr.u[jj], fb.u[jj]);
                }
#pragma unroll
                for (int m = 0; m < 8; ++m) {
                    sh8 Af = ldfrag(L + BIGO, m * 16 + lx, ko, 256);
                    acc2[m][0] = MFMA(Af, bA.v, acc2[m][0]);
                    acc2[m][1] = MFMA(Af, bB.v, acc2[m][1]);
                }
            }
            // ---- epilogue: fr3 GEMM through [16][40] quarters, h-outer so each
            // bW[4] load serves both cc halves
            f32x4 acc3[2][4];
#pragma unroll
            for (int cc = 0; cc < 2; ++cc)
#pragma unroll
                for (int n3 = 0; n3 < 4; ++n3) acc3[cc][n3] = (f32x4){0.f,0.f,0.f,0.f};
#pragma unroll
            for (int h = 0; h < 4; ++h) {
                sh8 bW[4];
#pragma unroll
                for (int n3 = 0; n3 < 4; ++n3)
                    bW[n3] = ldfrag(L + F3LO, n3 * 16 + lx, h * 32 + lq * 8, 128);
#pragma unroll
                for (int cc = 0; cc < 2; ++cc) {
                    stAct040(a2w, lx, lq * 4,      acc2[2 * h][cc]);
                    stAct040(a2w, lx, 16 + lq * 4, acc2[2 * h + 1][cc]);
                    sh8 af = ldfrag40(a2w, lx, lq * 8);
#pragma unroll
                    for (int n3 = 0; n3 < 4; ++n3)
                        acc3[cc][n3] = MFMA(af, bW[n3], acc3[cc][n3]);
                }
            }
#pragma unroll
            for (int cc = 0; cc < 2; ++cc) {
                bool mpad = (p == 1) && (cc == 1) && (lq == 3);
#pragma unroll
                for (int n3 = 0; n3 < 4; ++n3) {
                    float bv = b3c[n3];
                    float s = fmaxf(acc3[cc][n3][0] + bv, 0.f) + fmaxf(acc3[cc][n3][1] + bv, 0.f)
                            + fmaxf(acc3[cc][n3][2] + bv, 0.f);
                    float s3 = fmaxf(acc3[cc][n3][3] + bv, 0.f);
                    part[n3] += s + (mpad ? 0.f : s3);
                }
            }
        }
#pragma unroll
        for (int n3 = 0; n3 < 4; ++n3) {
            part[n3] += __shfl_xor(part[n3], 16, 64);
            part[n3] += __shfl_xor(part[n3], 32, 64);
        }
        if (lq == 0) {
#pragma unroll
            for (int n3 = 0; n3 < 4; ++n3)
                L[S1RO + sidx(r, n3 * 16 + lx, 256)] = f2h(part[n3]);
        }
    }
    __syncthreads();

    // ================= phase N =================
    // fo1 -> BIG (pure copy); recompute xnT into XNTP (a2w dead)
    wcopy(L + BIGO, wsw + W_FO1, 32768, t);
    for (int i = t; i < 4096; i += 768) {
        int n = i & 63, k = i >> 6;
        float v = (k < PP) ? x[b * PP * NN + k * NN + n] * scl[k] + bia[k] : 0.f;
        L[XNTP + sidx(n, k, 64)] = f2h(v);
    }
    __syncthreads();

    // L1N: M=256 (16 m-tiles over 12 waves), N=64 nodes, K=128
    // (ks 0,1 ebar from S1RO cols 0..63; ks 2,3 xn from XNTP)
    for (int mt = w; mt < 16; mt += 12) {
        f32x4 accN[4];
#pragma unroll
        for (int nt = 0; nt < 4; ++nt) accN[nt] = (f32x4){0.f,0.f,0.f,0.f};
#pragma unroll
        for (int ks = 0; ks < 4; ++ks) {
            sh8 Af = ldfrag(L + BIGO, mt * 16 + lx, ks * 32 + lq * 8, 128);
#pragma unroll
            for (int nt = 0; nt < 4; ++nt) {
                sh8 Bf = (ks < 2) ? ldfrag(L + S1RO, nt * 16 + lx, ks * 32 + lq * 8, 256)
                                  : ldfrag(L + XNTP, nt * 16 + lx, (ks - 2) * 32 + lq * 8, 64);
                accN[nt] = MFMA(Af, Bf, accN[nt]);
            }
        }
        int ch0 = mt * 16 + lq * 4;
        float4 bi = *(const float4*)(fo1_b + ch0);
#pragma unroll
        for (int nt = 0; nt < 4; ++nt)
            stAct(L + S1SO, nt * 16 + lx, ch0, 256, accN[nt], bi);
    }
    __syncthreads();   // BIG/S1RO/XNTP reads done

    // fo2 -> BIG, fo3 -> S1RO (pure copies)
    wcopy(L + BIGO, wsw + W_FO2, 32768, t);
    wcopy(L + S1RO, wsw + W_FO3, 8192, t);
    __syncthreads();

    // L2N: M=128 (waves 0..7), N=64, K=256 -> act2N @ F3LO [64][128]
    if (w < 8) {
        f32x4 a2N[4];
#pragma unroll
        for (int nt = 0; nt < 4; ++nt) a2N[nt] = (f32x4){0.f,0.f,0.f,0.f};
#pragma unroll
        for (int ks = 0; ks < 8; ++ks) {
            sh8 Af = ldfrag(L + BIGO, w * 16 + lx, ks * 32 + lq * 8, 256);
#pragma unroll
            for (int nt = 0; nt < 4; ++nt) {
                sh8 Bf = ldfrag(L + S1SO, nt * 16 + lx, ks * 32 + lq * 8, 256);
                a2N[nt] = MFMA(Af, Bf, a2N[nt]);
            }
        }
        int ch0 = w * 16 + lq * 4;
        float4 bi = *(const float4*)(fo2_b + ch0);
#pragma unroll
        for (int nt = 0; nt < 4; ++nt)
            stAct(L + F3LO, nt * 16 + lx, ch0, 128, a2N[nt], bi);
    }
    __syncthreads();

    // L3N: M=64 (fo3 ch), N=64 nodes, K=128 (waves 0..3); relu+bias, sum over nodes
    if (w < 4) {
        f32x4 a3N[4];
#pragma unroll
        for (int nt = 0; nt < 4; ++nt) a3N[nt] = (f32x4){0.f,0.f,0.f,0.f};
#pragma unroll
        for (int ks3 = 0; ks3 < 4; ++ks3) {
            sh8 Af = ldfrag(L + S1RO, 16 * w + lx, ks3 * 32 + lq * 8, 128);
#pragma unroll
            for (int nt = 0; nt < 4; ++nt) {
                sh8 Bf = ldfrag(L + F3LO, nt * 16 + lx, ks3 * 32 + lq * 8, 128);
                a3N[nt] = MFMA(Af, Bf, a3N[nt]);
            }
        }
        float4 b3 = *(const float4*)(fo3_b + 16 * w + lq * 4);
        float o0 = 0.f, o1 = 0.f, o2 = 0.f, o3 = 0.f;
#pragma unroll
        for (int nt = 0; nt < 4; ++nt) {
            o0 += fmaxf(a3N[nt][0] + b3.x, 0.f);
            o1 += fmaxf(a3N[nt][1] + b3.y, 0.f);
            o2 += fmaxf(a3N[nt][2] + b3.z, 0.f);
            o3 += fmaxf(a3N[nt][3] + b3.w, 0.f);
        }
#pragma unroll
        for (int off = 8; off >= 1; off >>= 1) {
            o0 += __shfl_xor(o0, off, 16);
            o1 += __shfl_xor(o1, off, 16);
            o2 += __shfl_xor(o2, off, 16);
            o3 += __shfl_xor(o3, off, 16);
        }
        if (lx == 0) {
            float* red = (float*)(L + REDO);
            *(float4*)&red[16 * w + lq * 4] = make_float4(o0, o1, o2, o3);
        }
    }
    __syncthreads();

    // ---- final FCs (fp32), wave-parallel: one 64-lane dot + reduce per output
    {
        float* red = (float*)(L + REDO);
        float* h1  = red + 64;
        float* h2  = red + 96;
        for (int o = w; o < 25; o += 12) {            // fc1: 25 out, k=64
            float v = fc1_w[o * 64 + l] * red[l];
#pragma unroll
            for (int off = 32; off >= 1; off >>= 1) v += __shfl_xor(v, off, 64);
            if (l == 0) h1[o] = v + fc1_b[o];
        }
        __syncthreads();
        for (int o = w; o < 15; o += 12) {            // fc2: 15 out, k=25
            float v = (l < 25) ? fc2_w[o * 25 + l] * h1[l] : 0.f;
#pragma unroll
            for (int off = 32; off >= 1; off >>= 1) v += __shfl_xor(v, off, 64);
            if (l == 0) h2[o] = v + fc2_b[o];
        }
        __syncthreads();
        if (w < 5) {                                   // fc3: 5 out, k=15
            float v = (l < 15) ? fc3_w[w * 15 + l] * h2[l] : 0.f;
#pragma unroll
            for (int off = 32; off >= 1; off >>= 1) v += __shfl_xor(v, off, 64);
            if (l == 0) out[b * 5 + w] = v + fc3_b[w];
        }
    }
}

extern "C" void kernel_launch(void* const* d_in, const int* in_sizes, int n_in,
                              void* d_out, int out_size, void* d_ws, size_t ws_size,
                              hipStream_t stream)
{
    const float* x        = (const float*)d_in[0];
    const float* bn_gamma = (const float*)d_in[3];
    const float* bn_beta  = (const float*)d_in[4];
    const float* fr1_w = (const float*)d_in[5];
    const float* fr1_b = (const float*)d_in[6];
    const float* fr2_w = (const float*)d_in[7];
    const float* fr2_b = (const float*)d_in[8];
    const float* fr3_w = (const float*)d_in[9];
    const float* fr3_b = (const float*)d_in[10];
    const float* fo1_w = (const float*)d_in[11];
    const float* fo1_b = (const float*)d_in[12];
    const float* fo2_w = (const float*)d_in[13];
    const float* fo2_b = (const float*)d_in[14];
    const float* fo3_w = (const float*)d_in[15];
    const float* fo3_b = (const float*)d_in[16];
    const float* fc1_w = (const float*)d_in[17];
    const float* fc1_b = (const float*)d_in[18];
    const float* fc2_w = (const float*)d_in[19];
    const float* fc2_b = (const float*)d_in[20];
    const float* fc3_w = (const float*)d_in[21];
    const float* fc3_b = (const float*)d_in[22];

    float* ws    = (float*)d_ws;
    float* scale = ws;
    float* bias  = ws + 64;
    ushort* wsw  = (ushort*)(ws + 128);   // W_TOT ushorts = 288 KB of f16 weights
    float* out   = (float*)d_out;

    // one fused dispatch: blocks 0..47 = bn stats; blocks 48..191 = weight prep
    bnprep_kernel<<<dim3(PP + W_TOT / 1024), dim3(1024), 0, stream>>>(
        x, bn_gamma, bn_beta, scale, bias,
        fr1_w, fr2_w, fr3_w, fo1_w, fo2_w, fo3_w, wsw);
    meg_kernel<<<dim3(BB), dim3(768), 0, stream>>>(
        x, scale, bias, wsw,
        fr1_b, fr2_b, fr3_b, fo1_b, fo2_b, fo3_b,
        fc1_w, fc1_b, fc2_w, fc2_b, fc3_w, fc3_b, out);
}